// Round 1
// baseline (589.271 us; speedup 1.0000x reference)
//
#include <hip/hip_runtime.h>
#include <hip/hip_bf16.h>

// Shapes (fixed per reference)
#define BB 8
#define LL 1024
#define EE 1024
#define HH 16
#define DHH 64
#define FFF 4096

typedef __attribute__((ext_vector_type(8))) short short8;
typedef __attribute__((ext_vector_type(4))) float f32x4;

__device__ inline f32x4 mfma16(short8 a, short8 b, f32x4 c) {
    return __builtin_amdgcn_mfma_f32_16x16x32_bf16(a, b, c, 0, 0, 0);
}

__device__ inline void async_ld16(const __hip_bfloat16* g, __hip_bfloat16* l) {
    __builtin_amdgcn_global_load_lds(
        (const __attribute__((address_space(1))) void*)g,
        (__attribute__((address_space(3))) void*)l, 16, 0, 0);
}

__device__ inline unsigned short bf16bits(float f) {
    __hip_bfloat16 h = __float2bfloat16(f);
    return *reinterpret_cast<unsigned short*>(&h);
}

// ---------------- elementwise f32 -> bf16 ----------------
__global__ __launch_bounds__(256) void cvt_bf16(const float* __restrict__ in,
                                                __hip_bfloat16* __restrict__ out) {
    size_t i = (size_t)blockIdx.x * 256 + threadIdx.x; // one float4 per thread
    float4 v = reinterpret_cast<const float4*>(in)[i];
    ushort4 o;
    o.x = bf16bits(v.x); o.y = bf16bits(v.y); o.z = bf16bits(v.z); o.w = bf16bits(v.w);
    reinterpret_cast<ushort4*>(out)[i] = o;
}

// ---------------- weight transpose+convert: dst[n*K+k] = src[k*N+n] ----------------
__global__ __launch_bounds__(256) void wtrans(const float* __restrict__ src,
                                              __hip_bfloat16* __restrict__ dst,
                                              int K, int N, long src_z, long dst_z) {
    src += (size_t)blockIdx.z * src_z;
    dst += (size_t)blockIdx.z * dst_z;
    __shared__ __hip_bfloat16 t[64 * 66]; // pad 66: strided phase conflict-free
    const int k0 = blockIdx.x * 64, n0 = blockIdx.y * 64;
    const int tid = threadIdx.x;
#pragma unroll
    for (int i = 0; i < 16; ++i) {
        int idx = tid + i * 256;
        int kr = idx >> 6, nc = idx & 63;
        t[kr * 66 + nc] = __float2bfloat16(src[(size_t)(k0 + kr) * N + n0 + nc]);
    }
    __syncthreads();
#pragma unroll
    for (int i = 0; i < 16; ++i) {
        int idx = tid + i * 256;
        int nr = idx >> 6, kc = idx & 63;
        dst[(size_t)(n0 + nr) * K + k0 + kc] = t[kc * 66 + nr];
    }
}

// ---------------- V transpose: qkv cols [2048..3072) -> vt[(b,h,d)][l] ----------------
__global__ __launch_bounds__(256) void vtrans(const __hip_bfloat16* __restrict__ qkv,
                                              __hip_bfloat16* __restrict__ vt) {
    const int bh = blockIdx.x, lt = blockIdx.y;
    const int b = bh >> 4, h = bh & 15;
    __shared__ __hip_bfloat16 t[64 * 66];
    const int tid = threadIdx.x;
#pragma unroll
    for (int i = 0; i < 16; ++i) {
        int idx = tid + i * 256;
        int lr = idx >> 6, d = idx & 63;
        t[lr * 66 + d] = qkv[(size_t)(b * LL + lt * 64 + lr) * 3072 + 2048 + h * 64 + d];
    }
    __syncthreads();
#pragma unroll
    for (int i = 0; i < 16; ++i) {
        int idx = tid + i * 256;
        int dr = idx >> 6, lc = idx & 63;
        vt[((size_t)bh * 64 + dr) * LL + lt * 64 + lc] = t[lc * 66 + dr];
    }
}

// ---------------- GEMM: C[M,N] = A[M,K] (bf16) x B^T[N,K] (bf16), f32 acc ----------------
// MODE 0: bf16 out, 3-range bias (QKV).  MODE 2: bf16 out, bias+relu.  MODE 3: f32 out, bias.
template <int MODE>
__global__ __launch_bounds__(256) void gemm_bf16(
    const __hip_bfloat16* __restrict__ A, const __hip_bfloat16* __restrict__ Bm,
    int M, int N, int K, void* __restrict__ Cout,
    const float* __restrict__ bias0, const float* __restrict__ bias1,
    const float* __restrict__ bias2) {
    __shared__ __hip_bfloat16 As[128 * 32];
    __shared__ __hip_bfloat16 Bs[128 * 32];
    const int m0 = blockIdx.x * 128, n0 = blockIdx.y * 128;
    const int tid = threadIdx.x;
    const int w = tid >> 6, l = tid & 63;
    const int lr = l & 15, lg = l >> 4;
    const int wr = (w >> 1) * 64, wc = (w & 1) * 64;

    f32x4 acc[4][4];
#pragma unroll
    for (int m = 0; m < 4; ++m)
#pragma unroll
        for (int n = 0; n < 4; ++n) acc[m][n] = (f32x4){0.f, 0.f, 0.f, 0.f};

    // staging: per wave 2 chunks of A (16 rows each) + 2 of B. lane -> row l/4, col (l%4)*8
    const __hip_bfloat16* ga = A + (size_t)(m0 + w * 32 + (l >> 2)) * K + ((l & 3) << 3);
    const __hip_bfloat16* gb = Bm + (size_t)(n0 + w * 32 + (l >> 2)) * K + ((l & 3) << 3);
    const size_t row16 = (size_t)16 * K;
    __hip_bfloat16* lA0 = As + (w * 32) * 32;
    __hip_bfloat16* lA1 = As + (w * 32 + 16) * 32;
    __hip_bfloat16* lB0 = Bs + (w * 32) * 32;
    __hip_bfloat16* lB1 = Bs + (w * 32 + 16) * 32;

    for (int kt = 0; kt < K; kt += 32) {
        __syncthreads();
        async_ld16(ga + kt, lA0);
        async_ld16(ga + kt + row16, lA1);
        async_ld16(gb + kt, lB0);
        async_ld16(gb + kt + row16, lB1);
        __syncthreads();
        short8 af[4], bfr[4];
#pragma unroll
        for (int m = 0; m < 4; ++m)
            af[m] = *reinterpret_cast<const short8*>(As + (wr + m * 16 + lr) * 32 + lg * 8);
#pragma unroll
        for (int n = 0; n < 4; ++n)
            bfr[n] = *reinterpret_cast<const short8*>(Bs + (wc + n * 16 + lr) * 32 + lg * 8);
#pragma unroll
        for (int m = 0; m < 4; ++m)
#pragma unroll
            for (int n = 0; n < 4; ++n) acc[m][n] = mfma16(af[m], bfr[n], acc[m][n]);
    }

#pragma unroll
    for (int n = 0; n < 4; ++n) {
        const int col = n0 + wc + n * 16 + lr;
        float bv;
        if constexpr (MODE == 0) {
            int s = col >> 10;
            const float* bp = (s == 0) ? bias0 : ((s == 1) ? bias1 : bias2);
            bv = bp[col & 1023];
        } else {
            bv = bias0[col];
        }
#pragma unroll
        for (int m = 0; m < 4; ++m) {
            const int row = m0 + wr + m * 16 + lg * 4;
#pragma unroll
            for (int r = 0; r < 4; ++r) {
                float v = acc[m][n][r] + bv;
                if constexpr (MODE == 2) v = fmaxf(v, 0.f);
                if constexpr (MODE == 0 || MODE == 2) {
                    ((__hip_bfloat16*)Cout)[(size_t)(row + r) * N + col] = __float2bfloat16(v);
                } else {
                    ((float*)Cout)[(size_t)(row + r) * N + col] = v;
                }
            }
        }
    }
}

// ---------------- flash attention ----------------
// block: one (b,h), 64 q-rows; 4 waves x 16 q-rows. KV tiles of 64.
__global__ __launch_bounds__(256) void attn(const __hip_bfloat16* __restrict__ qkv,
                                            const __hip_bfloat16* __restrict__ vt,
                                            __hip_bfloat16* __restrict__ cat) {
    const int bh = blockIdx.x, qt = blockIdx.y;
    const int b = bh >> 4, h = bh & 15;
    const int tid = threadIdx.x, w = tid >> 6, l = tid & 63;
    const int lr = l & 15, lg = l >> 4;
    __shared__ __hip_bfloat16 plds[4][16 * 64];

    const size_t qrow = (size_t)(b * LL + qt * 64 + w * 16 + lr);
    short8 qa[2];
    qa[0] = *reinterpret_cast<const short8*>(qkv + qrow * 3072 + h * 64 + lg * 8);
    qa[1] = *reinterpret_cast<const short8*>(qkv + qrow * 3072 + h * 64 + 32 + lg * 8);

    float mrun[4], lrun[4];
    f32x4 oacc[4];
#pragma unroll
    for (int r = 0; r < 4; ++r) { mrun[r] = -INFINITY; lrun[r] = 0.f; }
#pragma unroll
    for (int n = 0; n < 4; ++n) oacc[n] = (f32x4){0.f, 0.f, 0.f, 0.f};

    const __hip_bfloat16* vbase = vt + (size_t)bh * 64 * LL;

    for (int kt = 0; kt < 16; ++kt) {
        const int k0 = kt * 64;
        f32x4 s[4];
#pragma unroll
        for (int n = 0; n < 4; ++n) {
            const size_t krow = (size_t)(b * LL + k0 + n * 16 + lr) * 3072 + 1024 + h * 64;
            short8 kf0 = *reinterpret_cast<const short8*>(qkv + krow + lg * 8);
            short8 kf1 = *reinterpret_cast<const short8*>(qkv + krow + 32 + lg * 8);
            f32x4 t = (f32x4){0.f, 0.f, 0.f, 0.f};
            t = mfma16(qa[0], kf0, t);
            t = mfma16(qa[1], kf1, t);
            s[n] = t * 0.125f; // 1/sqrt(64)
        }
        float ps[4], alpha[4];
#pragma unroll
        for (int r = 0; r < 4; ++r) {
            float mx = fmaxf(fmaxf(s[0][r], s[1][r]), fmaxf(s[2][r], s[3][r]));
#pragma unroll
            for (int msk = 1; msk < 16; msk <<= 1) mx = fmaxf(mx, __shfl_xor(mx, msk, 64));
            float mnew = fmaxf(mrun[r], mx);
            alpha[r] = __expf(mrun[r] - mnew);
            mrun[r] = mnew;
            float p0 = 0.f;
#pragma unroll
            for (int n = 0; n < 4; ++n) {
                float p = __expf(s[n][r] - mnew);
                s[n][r] = p;
                p0 += p;
            }
#pragma unroll
            for (int msk = 1; msk < 16; msk <<= 1) p0 += __shfl_xor(p0, msk, 64);
            ps[r] = p0;
        }
#pragma unroll
        for (int r = 0; r < 4; ++r) lrun[r] = lrun[r] * alpha[r] + ps[r];
#pragma unroll
        for (int n = 0; n < 4; ++n)
#pragma unroll
            for (int r = 0; r < 4; ++r) oacc[n][r] *= alpha[r];

        // P (D-layout) -> LDS [16 q][64 k] per wave
#pragma unroll
        for (int n = 0; n < 4; ++n)
#pragma unroll
            for (int r = 0; r < 4; ++r)
                plds[w][(lg * 4 + r) * 64 + n * 16 + lr] = __float2bfloat16(s[n][r]);
        asm volatile("s_waitcnt lgkmcnt(0)" ::: "memory");

        short8 pa[2];
        pa[0] = *reinterpret_cast<const short8*>(&plds[w][lr * 64 + lg * 8]);
        pa[1] = *reinterpret_cast<const short8*>(&plds[w][lr * 64 + 32 + lg * 8]);
#pragma unroll
        for (int n = 0; n < 4; ++n) {
            const __hip_bfloat16* vr = vbase + (size_t)(n * 16 + lr) * LL + k0;
            short8 vf0 = *reinterpret_cast<const short8*>(vr + lg * 8);
            short8 vf1 = *reinterpret_cast<const short8*>(vr + 32 + lg * 8);
            oacc[n] = mfma16(pa[0], vf0, oacc[n]);
            oacc[n] = mfma16(pa[1], vf1, oacc[n]);
        }
    }
#pragma unroll
    for (int n = 0; n < 4; ++n)
#pragma unroll
        for (int r = 0; r < 4; ++r) {
            float v = oacc[n][r] / lrun[r];
            cat[(size_t)(b * LL + qt * 64 + w * 16 + lg * 4 + r) * EE + h * 64 + n * 16 + lr] =
                __float2bfloat16(v);
        }
}

// ---------------- LayerNorm over E=1024: out = gamma*(a+b - mean)/sqrt(var+eps)+beta ----------------
__global__ __launch_bounds__(256) void ln_ker(const float* __restrict__ a,
                                              const float* __restrict__ b,
                                              const float* __restrict__ gamma,
                                              const float* __restrict__ beta,
                                              float* __restrict__ outf,
                                              __hip_bfloat16* __restrict__ outb) {
    const int row = blockIdx.x, tid = threadIdx.x;
    const size_t base = (size_t)row * EE;
    float4 x = reinterpret_cast<const float4*>(a + base)[tid];
    float4 y = reinterpret_cast<const float4*>(b + base)[tid];
    x.x += y.x; x.y += y.y; x.z += y.z; x.w += y.w;
    float s = x.x + x.y + x.z + x.w;
    float s2 = x.x * x.x + x.y * x.y + x.z * x.z + x.w * x.w;
#pragma unroll
    for (int msk = 1; msk < 64; msk <<= 1) {
        s += __shfl_xor(s, msk, 64);
        s2 += __shfl_xor(s2, msk, 64);
    }
    __shared__ float red[8];
    const int w = tid >> 6, l = tid & 63;
    if (l == 0) { red[w] = s; red[4 + w] = s2; }
    __syncthreads();
    s = red[0] + red[1] + red[2] + red[3];
    s2 = red[4] + red[5] + red[6] + red[7];
    const float mean = s * (1.f / 1024.f);
    const float var = s2 * (1.f / 1024.f) - mean * mean;
    const float rstd = rsqrtf(var + 1e-10f);
    float4 g = reinterpret_cast<const float4*>(gamma)[tid];
    float4 bt = reinterpret_cast<const float4*>(beta)[tid];
    float4 o;
    o.x = g.x * (x.x - mean) * rstd + bt.x;
    o.y = g.y * (x.y - mean) * rstd + bt.y;
    o.z = g.z * (x.z - mean) * rstd + bt.z;
    o.w = g.w * (x.w - mean) * rstd + bt.w;
    reinterpret_cast<float4*>(outf + base)[tid] = o;
    if (outb) {
        ushort4 ob;
        ob.x = bf16bits(o.x); ob.y = bf16bits(o.y); ob.z = bf16bits(o.z); ob.w = bf16bits(o.w);
        reinterpret_cast<ushort4*>(outb + base)[tid] = ob;
    }
}

extern "C" void kernel_launch(void* const* d_in, const int* in_sizes, int n_in,
                              void* d_out, int out_size, void* d_ws, size_t ws_size,
                              hipStream_t stream) {
    const float* x = (const float*)d_in[0];
    const float* Wq = (const float*)d_in[1];
    const float* bq = (const float*)d_in[2];
    const float* Wk = (const float*)d_in[3];
    const float* bk = (const float*)d_in[4];
    const float* Wv = (const float*)d_in[5];
    const float* bv = (const float*)d_in[6];
    const float* Wo = (const float*)d_in[7];
    const float* bo = (const float*)d_in[8];
    const float* W1 = (const float*)d_in[9];
    const float* b1 = (const float*)d_in[10];
    const float* W2 = (const float*)d_in[11];
    const float* b2 = (const float*)d_in[12];
    const float* gamma1 = (const float*)d_in[13];
    const float* beta1 = (const float*)d_in[14];
    const float* gamma2 = (const float*)d_in[15];
    const float* beta2 = (const float*)d_in[16];
    float* out = (float*)d_out;

    char* Wb = (char*)d_ws;
    const size_t MB = (size_t)1 << 20;
    if (ws_size < 168 * MB) return;
    __hip_bfloat16* xb = (__hip_bfloat16*)(Wb + 0 * MB);        // 16 MB
    __hip_bfloat16* wqkvt = (__hip_bfloat16*)(Wb + 16 * MB);    // 6 MB  [3072][1024]
    __hip_bfloat16* wot = (__hip_bfloat16*)(Wb + 22 * MB);      // 2 MB  [1024][1024]
    __hip_bfloat16* w1t = (__hip_bfloat16*)(Wb + 24 * MB);      // 8 MB  [4096][1024]
    __hip_bfloat16* w2t = (__hip_bfloat16*)(Wb + 32 * MB);      // 8 MB  [1024][4096]
    __hip_bfloat16* qkvb = (__hip_bfloat16*)(Wb + 40 * MB);     // 48 MB [8192][3072]
    __hip_bfloat16* vtb = (__hip_bfloat16*)(Wb + 88 * MB);      // 16 MB [128*64][1024]
    __hip_bfloat16* catb = (__hip_bfloat16*)(Wb + 104 * MB);    // 16 MB [8192][1024]
    float* out2f = (float*)(Wb + 120 * MB);                     // 32 MB
    __hip_bfloat16* out2b = (__hip_bfloat16*)(Wb + 152 * MB);   // 16 MB
    __hip_bfloat16* hbuf = (__hip_bfloat16*)(Wb + 40 * MB);     // 64 MB, reuses qkv+vt

    // 1. convert x
    cvt_bf16<<<8192, 256, 0, stream>>>(x, xb);
    // 2. weights -> [N,K] bf16
    wtrans<<<dim3(16, 1, 16), 256, 0, stream>>>(Wq, wqkvt, 1024, 64, 65536, 65536);
    wtrans<<<dim3(16, 1, 16), 256, 0, stream>>>(Wk, wqkvt + 1024 * 1024, 1024, 64, 65536, 65536);
    wtrans<<<dim3(16, 1, 16), 256, 0, stream>>>(Wv, wqkvt + 2048 * 1024, 1024, 64, 65536, 65536);
    wtrans<<<dim3(16, 16, 1), 256, 0, stream>>>(Wo, wot, 1024, 1024, 0, 0);
    wtrans<<<dim3(16, 64, 1), 256, 0, stream>>>(W1, w1t, 1024, 4096, 0, 0);
    wtrans<<<dim3(64, 16, 1), 256, 0, stream>>>(W2, w2t, 4096, 1024, 0, 0);
    // 3. QKV projection
    gemm_bf16<0><<<dim3(64, 24), 256, 0, stream>>>(xb, wqkvt, 8192, 3072, 1024, qkvb, bq, bk, bv);
    // 4. V transpose per head
    vtrans<<<dim3(128, 16), 256, 0, stream>>>(qkvb, vtb);
    // 5. attention
    attn<<<dim3(128, 16), 256, 0, stream>>>(qkvb, vtb, catb);
    // 6. output projection (f32 into d_out as scratch)
    gemm_bf16<3><<<dim3(64, 8), 256, 0, stream>>>(catb, wot, 8192, 1024, 1024, out, bo, nullptr, nullptr);
    // 7. LN1: LN(out1 + x) -> out2 (f32 + bf16)
    ln_ker<<<8192, 256, 0, stream>>>(out, x, gamma1, beta1, out2f, out2b);
    // 8. FFN1 + ReLU
    gemm_bf16<2><<<dim3(64, 32), 256, 0, stream>>>(out2b, w1t, 8192, 4096, 1024, hbuf, b1, nullptr, nullptr);
    // 9. FFN2 (f32 into d_out)
    gemm_bf16<3><<<dim3(64, 8), 256, 0, stream>>>(hbuf, w2t, 8192, 1024, 4096, out, b2, nullptr, nullptr);
    // 10. LN2 in-place: LN(out3 + out2) -> d_out
    ln_ker<<<8192, 256, 0, stream>>>(out, out2f, gamma2, beta2, out, nullptr);
}

// Round 2
// 478.675 us; speedup vs baseline: 1.2310x; 1.2310x over previous
//
#include <hip/hip_runtime.h>
#include <hip/hip_bf16.h>

// Shapes (fixed per reference)
#define BB 8
#define LL 1024
#define EE 1024
#define HH 16
#define DHH 64
#define FFF 4096

typedef __attribute__((ext_vector_type(8))) short short8;
typedef __attribute__((ext_vector_type(4))) float f32x4;

__device__ inline f32x4 mfma16(short8 a, short8 b, f32x4 c) {
    return __builtin_amdgcn_mfma_f32_16x16x32_bf16(a, b, c, 0, 0, 0);
}

__device__ inline void async_ld16(const __hip_bfloat16* g, __hip_bfloat16* l) {
    __builtin_amdgcn_global_load_lds(
        (const __attribute__((address_space(1))) void*)g,
        (__attribute__((address_space(3))) void*)l, 16, 0, 0);
}

__device__ inline unsigned short bf16bits(float f) {
    __hip_bfloat16 h = __float2bfloat16(f);
    return *reinterpret_cast<unsigned short*>(&h);
}

// ---------------- elementwise f32 -> bf16 ----------------
__global__ __launch_bounds__(256) void cvt_bf16(const float* __restrict__ in,
                                                __hip_bfloat16* __restrict__ out) {
    size_t i = (size_t)blockIdx.x * 256 + threadIdx.x; // one float4 per thread
    float4 v = reinterpret_cast<const float4*>(in)[i];
    ushort4 o;
    o.x = bf16bits(v.x); o.y = bf16bits(v.y); o.z = bf16bits(v.z); o.w = bf16bits(v.w);
    reinterpret_cast<ushort4*>(out)[i] = o;
}

// ---------------- weight transpose+convert: dst[n*K+k] = src[k*N+n] ----------------
__global__ __launch_bounds__(256) void wtrans(const float* __restrict__ src,
                                              __hip_bfloat16* __restrict__ dst,
                                              int K, int N, long src_z, long dst_z) {
    src += (size_t)blockIdx.z * src_z;
    dst += (size_t)blockIdx.z * dst_z;
    __shared__ __hip_bfloat16 t[64 * 66]; // pad 66: strided phase conflict-free
    const int k0 = blockIdx.x * 64, n0 = blockIdx.y * 64;
    const int tid = threadIdx.x;
#pragma unroll
    for (int i = 0; i < 16; ++i) {
        int idx = tid + i * 256;
        int kr = idx >> 6, nc = idx & 63;
        t[kr * 66 + nc] = __float2bfloat16(src[(size_t)(k0 + kr) * N + n0 + nc]);
    }
    __syncthreads();
#pragma unroll
    for (int i = 0; i < 16; ++i) {
        int idx = tid + i * 256;
        int nr = idx >> 6, kc = idx & 63;
        dst[(size_t)(n0 + nr) * K + k0 + kc] = t[kc * 66 + nr];
    }
}

// ---------------- V transpose: qkv cols [2048..3072) -> vt[(b,h,d)][l] ----------------
__global__ __launch_bounds__(256) void vtrans(const __hip_bfloat16* __restrict__ qkv,
                                              __hip_bfloat16* __restrict__ vt) {
    const int bh = blockIdx.x, lt = blockIdx.y;
    const int b = bh >> 4, h = bh & 15;
    __shared__ __hip_bfloat16 t[64 * 66];
    const int tid = threadIdx.x;
#pragma unroll
    for (int i = 0; i < 16; ++i) {
        int idx = tid + i * 256;
        int lr = idx >> 6, d = idx & 63;
        t[lr * 66 + d] = qkv[(size_t)(b * LL + lt * 64 + lr) * 3072 + 2048 + h * 64 + d];
    }
    __syncthreads();
#pragma unroll
    for (int i = 0; i < 16; ++i) {
        int idx = tid + i * 256;
        int dr = idx >> 6, lc = idx & 63;
        vt[((size_t)bh * 64 + dr) * LL + lt * 64 + lc] = t[lc * 66 + dr];
    }
}

// ---------------- GEMM: C[M,N] = A[M,K] (bf16) x B^T[N,K] (bf16), f32 acc ----------------
// MODE 0: bf16 out, 3-range bias (QKV).  MODE 2: bf16 out, bias+relu.  MODE 3: f32 out, bias.
template <int MODE>
__global__ __launch_bounds__(256) void gemm_bf16(
    const __hip_bfloat16* __restrict__ A, const __hip_bfloat16* __restrict__ Bm,
    int M, int N, int K, void* __restrict__ Cout,
    const float* __restrict__ bias0, const float* __restrict__ bias1,
    const float* __restrict__ bias2) {
    __shared__ __hip_bfloat16 As[128 * 32];
    __shared__ __hip_bfloat16 Bs[128 * 32];
    const int m0 = blockIdx.x * 128, n0 = blockIdx.y * 128;
    const int tid = threadIdx.x;
    const int w = tid >> 6, l = tid & 63;
    const int lr = l & 15, lg = l >> 4;
    const int wr = (w >> 1) * 64, wc = (w & 1) * 64;

    f32x4 acc[4][4];
#pragma unroll
    for (int m = 0; m < 4; ++m)
#pragma unroll
        for (int n = 0; n < 4; ++n) acc[m][n] = (f32x4){0.f, 0.f, 0.f, 0.f};

    // staging: per wave 2 chunks of A (16 rows each) + 2 of B. lane -> row l/4, col (l%4)*8
    const __hip_bfloat16* ga = A + (size_t)(m0 + w * 32 + (l >> 2)) * K + ((l & 3) << 3);
    const __hip_bfloat16* gb = Bm + (size_t)(n0 + w * 32 + (l >> 2)) * K + ((l & 3) << 3);
    const size_t row16 = (size_t)16 * K;
    __hip_bfloat16* lA0 = As + (w * 32) * 32;
    __hip_bfloat16* lA1 = As + (w * 32 + 16) * 32;
    __hip_bfloat16* lB0 = Bs + (w * 32) * 32;
    __hip_bfloat16* lB1 = Bs + (w * 32 + 16) * 32;

    for (int kt = 0; kt < K; kt += 32) {
        __syncthreads();
        async_ld16(ga + kt, lA0);
        async_ld16(ga + kt + row16, lA1);
        async_ld16(gb + kt, lB0);
        async_ld16(gb + kt + row16, lB1);
        __syncthreads();
        short8 af[4], bfr[4];
#pragma unroll
        for (int m = 0; m < 4; ++m)
            af[m] = *reinterpret_cast<const short8*>(As + (wr + m * 16 + lr) * 32 + lg * 8);
#pragma unroll
        for (int n = 0; n < 4; ++n)
            bfr[n] = *reinterpret_cast<const short8*>(Bs + (wc + n * 16 + lr) * 32 + lg * 8);
#pragma unroll
        for (int m = 0; m < 4; ++m)
#pragma unroll
            for (int n = 0; n < 4; ++n) acc[m][n] = mfma16(af[m], bfr[n], acc[m][n]);
    }

#pragma unroll
    for (int n = 0; n < 4; ++n) {
        const int col = n0 + wc + n * 16 + lr;
        float bv;
        if constexpr (MODE == 0) {
            int s = col >> 10;
            const float* bp = (s == 0) ? bias0 : ((s == 1) ? bias1 : bias2);
            bv = bp[col & 1023];
        } else {
            bv = bias0[col];
        }
#pragma unroll
        for (int m = 0; m < 4; ++m) {
            const int row = m0 + wr + m * 16 + lg * 4;
#pragma unroll
            for (int r = 0; r < 4; ++r) {
                float v = acc[m][n][r] + bv;
                if constexpr (MODE == 2) v = fmaxf(v, 0.f);
                if constexpr (MODE == 0 || MODE == 2) {
                    ((__hip_bfloat16*)Cout)[(size_t)(row + r) * N + col] = __float2bfloat16(v);
                } else {
                    ((float*)Cout)[(size_t)(row + r) * N + col] = v;
                }
            }
        }
    }
}

// ---------------- flash attention v2 ----------------
// block: one (b,h) x 64 q-rows; 4 waves x 16 q-rows. KV tiles of 64, double-buffered in LDS.
// K/V tiles staged cooperatively via global_load_lds (linear dest) with the XOR swizzle
// applied on the GLOBAL source address (rule: both-sides-or-neither); reads use the same XOR.
__global__ __launch_bounds__(256) void attn2(const __hip_bfloat16* __restrict__ qkv,
                                             const __hip_bfloat16* __restrict__ vt,
                                             __hip_bfloat16* __restrict__ cat) {
    const int qt = blockIdx.x, bh = blockIdx.y;
    const int b = bh >> 4, h = bh & 15;
    const int tid = threadIdx.x, w = tid >> 6, l = tid & 63;
    const int lr = l & 15, lg = l >> 4;

    __shared__ __hip_bfloat16 Ks[2][64 * 64]; // [kv][d], chunk-swizzled
    __shared__ __hip_bfloat16 Vs[2][64 * 64]; // [d][kv], chunk-swizzled
    __shared__ __hip_bfloat16 plds[4][16 * 72]; // pad 72 (144B stride): <=2-way

    // Q fragments (row = q, 64 contraction elems in 2 frags)
    const size_t qrow = (size_t)(b * LL + qt * 64 + w * 16 + lr);
    const short8 qa0 = *reinterpret_cast<const short8*>(qkv + qrow * 3072 + h * 64 + lg * 8);
    const short8 qa1 = *reinterpret_cast<const short8*>(qkv + qrow * 3072 + h * 64 + 32 + lg * 8);

    // staging: 512 16B-chunks per tile (64 rows x 8 chunks); wave w covers chunk
    // ranges [w*64, w*64+64) and [256+w*64, ...). lane chunk c: row=c>>3, lds chunk=c&7,
    // global chunk = (c&7) ^ (row&7)  (inverse swizzle on the source).
    const int cA = w * 64 + l, cB = 256 + w * 64 + l;
    const int rA = cA >> 3, sA = (((cA & 7) ^ (rA & 7)) << 3);
    const int rB = cB >> 3, sB = (((cB & 7) ^ (rB & 7)) << 3);
    const __hip_bfloat16* kgA = qkv + (size_t)(b * LL + rA) * 3072 + 1024 + h * 64 + sA;
    const __hip_bfloat16* kgB = qkv + (size_t)(b * LL + rB) * 3072 + 1024 + h * 64 + sB;
    const __hip_bfloat16* vgA = vt + ((size_t)bh * 64 + rA) * LL + sA;
    const __hip_bfloat16* vgB = vt + ((size_t)bh * 64 + rB) * LL + sB;

#define STAGE_KV(bi, k0)                                                     \
    do {                                                                     \
        async_ld16(kgA + (size_t)(k0) * 3072, &Ks[bi][(w * 64) * 8]);        \
        async_ld16(kgB + (size_t)(k0) * 3072, &Ks[bi][(256 + w * 64) * 8]);  \
        async_ld16(vgA + (k0), &Vs[bi][(w * 64) * 8]);                       \
        async_ld16(vgB + (k0), &Vs[bi][(256 + w * 64) * 8]);                 \
    } while (0)

    float mrun[4], lrun[4];
    f32x4 oacc[4];
#pragma unroll
    for (int r = 0; r < 4; ++r) { mrun[r] = -INFINITY; lrun[r] = 0.f; }
#pragma unroll
    for (int n = 0; n < 4; ++n) oacc[n] = (f32x4){0.f, 0.f, 0.f, 0.f};

    STAGE_KV(0, 0);
    asm volatile("s_waitcnt vmcnt(0)" ::: "memory");
    __syncthreads();

    int cur = 0;
    for (int kt = 0; kt < 16; ++kt) {
        if (kt < 15) STAGE_KV(cur ^ 1, (kt + 1) * 64);

        // QK^T from swizzled K tile
        f32x4 s[4];
#pragma unroll
        for (int n = 0; n < 4; ++n) {
            const int krow = n * 16 + lr;
            const int sw = krow & 7;
            const short8 kf0 =
                *reinterpret_cast<const short8*>(&Ks[cur][krow * 64 + ((lg ^ sw) << 3)]);
            const short8 kf1 =
                *reinterpret_cast<const short8*>(&Ks[cur][krow * 64 + (((lg + 4) ^ sw) << 3)]);
            f32x4 t = (f32x4){0.f, 0.f, 0.f, 0.f};
            t = mfma16(qa0, kf0, t);
            t = mfma16(qa1, kf1, t);
            s[n] = t * 0.125f; // 1/sqrt(64)
        }
        // online softmax (rows q = lg*4+r, cols k spread over lr x n)
        float ps[4], alpha[4];
#pragma unroll
        for (int r = 0; r < 4; ++r) {
            float mx = fmaxf(fmaxf(s[0][r], s[1][r]), fmaxf(s[2][r], s[3][r]));
#pragma unroll
            for (int msk = 1; msk < 16; msk <<= 1) mx = fmaxf(mx, __shfl_xor(mx, msk, 64));
            float mnew = fmaxf(mrun[r], mx);
            alpha[r] = __expf(mrun[r] - mnew);
            mrun[r] = mnew;
            float p0 = 0.f;
#pragma unroll
            for (int n = 0; n < 4; ++n) {
                float p = __expf(s[n][r] - mnew);
                s[n][r] = p;
                p0 += p;
            }
#pragma unroll
            for (int msk = 1; msk < 16; msk <<= 1) p0 += __shfl_xor(p0, msk, 64);
            ps[r] = p0;
        }
#pragma unroll
        for (int r = 0; r < 4; ++r) lrun[r] = lrun[r] * alpha[r] + ps[r];
#pragma unroll
        for (int n = 0; n < 4; ++n)
#pragma unroll
            for (int r = 0; r < 4; ++r) oacc[n][r] *= alpha[r];

        // P (D-layout) -> per-wave LDS [16 q][72] -> A-layout frags
#pragma unroll
        for (int n = 0; n < 4; ++n)
#pragma unroll
            for (int r = 0; r < 4; ++r)
                plds[w][(lg * 4 + r) * 72 + n * 16 + lr] = __float2bfloat16(s[n][r]);
        asm volatile("s_waitcnt lgkmcnt(0)" ::: "memory");
        __builtin_amdgcn_sched_barrier(0);

        const short8 pa0 = *reinterpret_cast<const short8*>(&plds[w][lr * 72 + lg * 8]);
        const short8 pa1 = *reinterpret_cast<const short8*>(&plds[w][lr * 72 + 32 + lg * 8]);
#pragma unroll
        for (int n = 0; n < 4; ++n) {
            const int vrow = n * 16 + lr;
            const int sw = vrow & 7;
            const short8 vf0 =
                *reinterpret_cast<const short8*>(&Vs[cur][vrow * 64 + ((lg ^ sw) << 3)]);
            const short8 vf1 =
                *reinterpret_cast<const short8*>(&Vs[cur][vrow * 64 + (((lg + 4) ^ sw) << 3)]);
            oacc[n] = mfma16(pa0, vf0, oacc[n]);
            oacc[n] = mfma16(pa1, vf1, oacc[n]);
        }

        asm volatile("s_waitcnt vmcnt(0)" ::: "memory");
        __syncthreads();
        cur ^= 1;
    }
#undef STAGE_KV

#pragma unroll
    for (int n = 0; n < 4; ++n)
#pragma unroll
        for (int r = 0; r < 4; ++r) {
            float v = oacc[n][r] / lrun[r];
            cat[(size_t)(b * LL + qt * 64 + w * 16 + lg * 4 + r) * EE + h * 64 + n * 16 + lr] =
                __float2bfloat16(v);
        }
}

// ---------------- LayerNorm over E=1024: out = gamma*(a+b - mean)/sqrt(var+eps)+beta ----------------
__global__ __launch_bounds__(256) void ln_ker(const float* __restrict__ a,
                                              const float* __restrict__ b,
                                              const float* __restrict__ gamma,
                                              const float* __restrict__ beta,
                                              float* __restrict__ outf,
                                              __hip_bfloat16* __restrict__ outb) {
    const int row = blockIdx.x, tid = threadIdx.x;
    const size_t base = (size_t)row * EE;
    float4 x = reinterpret_cast<const float4*>(a + base)[tid];
    float4 y = reinterpret_cast<const float4*>(b + base)[tid];
    x.x += y.x; x.y += y.y; x.z += y.z; x.w += y.w;
    float s = x.x + x.y + x.z + x.w;
    float s2 = x.x * x.x + x.y * x.y + x.z * x.z + x.w * x.w;
#pragma unroll
    for (int msk = 1; msk < 64; msk <<= 1) {
        s += __shfl_xor(s, msk, 64);
        s2 += __shfl_xor(s2, msk, 64);
    }
    __shared__ float red[8];
    const int w = tid >> 6, l = tid & 63;
    if (l == 0) { red[w] = s; red[4 + w] = s2; }
    __syncthreads();
    s = red[0] + red[1] + red[2] + red[3];
    s2 = red[4] + red[5] + red[6] + red[7];
    const float mean = s * (1.f / 1024.f);
    const float var = s2 * (1.f / 1024.f) - mean * mean;
    const float rstd = rsqrtf(var + 1e-10f);
    float4 g = reinterpret_cast<const float4*>(gamma)[tid];
    float4 bt = reinterpret_cast<const float4*>(beta)[tid];
    float4 o;
    o.x = g.x * (x.x - mean) * rstd + bt.x;
    o.y = g.y * (x.y - mean) * rstd + bt.y;
    o.z = g.z * (x.z - mean) * rstd + bt.z;
    o.w = g.w * (x.w - mean) * rstd + bt.w;
    reinterpret_cast<float4*>(outf + base)[tid] = o;
    if (outb) {
        ushort4 ob;
        ob.x = bf16bits(o.x); ob.y = bf16bits(o.y); ob.z = bf16bits(o.z); ob.w = bf16bits(o.w);
        reinterpret_cast<ushort4*>(outb + base)[tid] = ob;
    }
}

extern "C" void kernel_launch(void* const* d_in, const int* in_sizes, int n_in,
                              void* d_out, int out_size, void* d_ws, size_t ws_size,
                              hipStream_t stream) {
    const float* x = (const float*)d_in[0];
    const float* Wq = (const float*)d_in[1];
    const float* bq = (const float*)d_in[2];
    const float* Wk = (const float*)d_in[3];
    const float* bk = (const float*)d_in[4];
    const float* Wv = (const float*)d_in[5];
    const float* bv = (const float*)d_in[6];
    const float* Wo = (const float*)d_in[7];
    const float* bo = (const float*)d_in[8];
    const float* W1 = (const float*)d_in[9];
    const float* b1 = (const float*)d_in[10];
    const float* W2 = (const float*)d_in[11];
    const float* b2 = (const float*)d_in[12];
    const float* gamma1 = (const float*)d_in[13];
    const float* beta1 = (const float*)d_in[14];
    const float* gamma2 = (const float*)d_in[15];
    const float* beta2 = (const float*)d_in[16];
    float* out = (float*)d_out;

    char* Wb = (char*)d_ws;
    const size_t MB = (size_t)1 << 20;
    if (ws_size < 168 * MB) return;
    __hip_bfloat16* xb = (__hip_bfloat16*)(Wb + 0 * MB);        // 16 MB
    __hip_bfloat16* wqkvt = (__hip_bfloat16*)(Wb + 16 * MB);    // 6 MB  [3072][1024]
    __hip_bfloat16* wot = (__hip_bfloat16*)(Wb + 22 * MB);      // 2 MB  [1024][1024]
    __hip_bfloat16* w1t = (__hip_bfloat16*)(Wb + 24 * MB);      // 8 MB  [4096][1024]
    __hip_bfloat16* w2t = (__hip_bfloat16*)(Wb + 32 * MB);      // 8 MB  [1024][4096]
    __hip_bfloat16* qkvb = (__hip_bfloat16*)(Wb + 40 * MB);     // 48 MB [8192][3072]
    __hip_bfloat16* vtb = (__hip_bfloat16*)(Wb + 88 * MB);      // 16 MB [128*64][1024]
    __hip_bfloat16* catb = (__hip_bfloat16*)(Wb + 104 * MB);    // 16 MB [8192][1024]
    float* out2f = (float*)(Wb + 120 * MB);                     // 32 MB
    __hip_bfloat16* out2b = (__hip_bfloat16*)(Wb + 152 * MB);   // 16 MB
    __hip_bfloat16* hbuf = (__hip_bfloat16*)(Wb + 40 * MB);     // 64 MB, reuses qkv+vt

    // 1. convert x
    cvt_bf16<<<8192, 256, 0, stream>>>(x, xb);
    // 2. weights -> [N,K] bf16
    wtrans<<<dim3(16, 1, 16), 256, 0, stream>>>(Wq, wqkvt, 1024, 64, 65536, 65536);
    wtrans<<<dim3(16, 1, 16), 256, 0, stream>>>(Wk, wqkvt + 1024 * 1024, 1024, 64, 65536, 65536);
    wtrans<<<dim3(16, 1, 16), 256, 0, stream>>>(Wv, wqkvt + 2048 * 1024, 1024, 64, 65536, 65536);
    wtrans<<<dim3(16, 16, 1), 256, 0, stream>>>(Wo, wot, 1024, 1024, 0, 0);
    wtrans<<<dim3(16, 64, 1), 256, 0, stream>>>(W1, w1t, 1024, 4096, 0, 0);
    wtrans<<<dim3(64, 16, 1), 256, 0, stream>>>(W2, w2t, 4096, 1024, 0, 0);
    // 3. QKV projection
    gemm_bf16<0><<<dim3(64, 24), 256, 0, stream>>>(xb, wqkvt, 8192, 3072, 1024, qkvb, bq, bk, bv);
    // 4. V transpose per head
    vtrans<<<dim3(128, 16), 256, 0, stream>>>(qkvb, vtb);
    // 5. attention (double-buffered LDS K/V, swizzled)
    attn2<<<dim3(16, 128), 256, 0, stream>>>(qkvb, vtb, catb);
    // 6. output projection (f32 into d_out as scratch)
    gemm_bf16<3><<<dim3(64, 8), 256, 0, stream>>>(catb, wot, 8192, 1024, 1024, out, bo, nullptr, nullptr);
    // 7. LN1: LN(out1 + x) -> out2 (f32 + bf16)
    ln_ker<<<8192, 256, 0, stream>>>(out, x, gamma1, beta1, out2f, out2b);
    // 8. FFN1 + ReLU
    gemm_bf16<2><<<dim3(64, 32), 256, 0, stream>>>(out2b, w1t, 8192, 4096, 1024, hbuf, b1, nullptr, nullptr);
    // 9. FFN2 (f32 into d_out)
    gemm_bf16<3><<<dim3(64, 8), 256, 0, stream>>>(hbuf, w2t, 8192, 1024, 4096, out, b2, nullptr, nullptr);
    // 10. LN2 in-place: LN(out3 + out2) -> d_out
    ln_ker<<<8192, 256, 0, stream>>>(out, out2f, gamma2, beta2, out, nullptr);
}

// Round 3
// 472.458 us; speedup vs baseline: 1.2472x; 1.0132x over previous
//
#include <hip/hip_runtime.h>
#include <hip/hip_bf16.h>

// Shapes (fixed per reference)
#define BB 8
#define LL 1024
#define EE 1024
#define HH 16
#define DHH 64
#define FFF 4096

typedef __attribute__((ext_vector_type(8))) short short8;
typedef __attribute__((ext_vector_type(4))) float f32x4;

__device__ inline f32x4 mfma16(short8 a, short8 b, f32x4 c) {
    return __builtin_amdgcn_mfma_f32_16x16x32_bf16(a, b, c, 0, 0, 0);
}

__device__ inline void async_ld16(const __hip_bfloat16* g, __hip_bfloat16* l) {
    __builtin_amdgcn_global_load_lds(
        (const __attribute__((address_space(1))) void*)g,
        (__attribute__((address_space(3))) void*)l, 16, 0, 0);
}

__device__ inline unsigned short bf16bits(float f) {
    __hip_bfloat16 h = __float2bfloat16(f);
    return *reinterpret_cast<unsigned short*>(&h);
}

// raw workgroup barrier (no implicit vmcnt(0) drain), with compiler memory fence
__device__ inline void wg_barrier() {
    asm volatile("" ::: "memory");
    __builtin_amdgcn_s_barrier();
    asm volatile("" ::: "memory");
}

// ---------------- elementwise f32 -> bf16 ----------------
__global__ __launch_bounds__(256) void cvt_bf16(const float* __restrict__ in,
                                                __hip_bfloat16* __restrict__ out) {
    size_t i = (size_t)blockIdx.x * 256 + threadIdx.x; // one float4 per thread
    float4 v = reinterpret_cast<const float4*>(in)[i];
    ushort4 o;
    o.x = bf16bits(v.x); o.y = bf16bits(v.y); o.z = bf16bits(v.z); o.w = bf16bits(v.w);
    reinterpret_cast<ushort4*>(out)[i] = o;
}

// ---------------- weight transpose+convert: dst[n*K+k] = src[k*N+n] ----------------
__global__ __launch_bounds__(256) void wtrans(const float* __restrict__ src,
                                              __hip_bfloat16* __restrict__ dst,
                                              int K, int N, long src_z, long dst_z) {
    src += (size_t)blockIdx.z * src_z;
    dst += (size_t)blockIdx.z * dst_z;
    __shared__ __hip_bfloat16 t[64 * 66]; // pad 66: strided phase conflict-free
    const int k0 = blockIdx.x * 64, n0 = blockIdx.y * 64;
    const int tid = threadIdx.x;
#pragma unroll
    for (int i = 0; i < 16; ++i) {
        int idx = tid + i * 256;
        int kr = idx >> 6, nc = idx & 63;
        t[kr * 66 + nc] = __float2bfloat16(src[(size_t)(k0 + kr) * N + n0 + nc]);
    }
    __syncthreads();
#pragma unroll
    for (int i = 0; i < 16; ++i) {
        int idx = tid + i * 256;
        int nr = idx >> 6, kc = idx & 63;
        dst[(size_t)(n0 + nr) * K + k0 + kc] = t[kc * 66 + nr];
    }
}

// ---------------- V transpose: qkv cols [2048..3072) -> vt[(b,h,d)][l] ----------------
__global__ __launch_bounds__(256) void vtrans(const __hip_bfloat16* __restrict__ qkv,
                                              __hip_bfloat16* __restrict__ vt) {
    const int bh = blockIdx.x, lt = blockIdx.y;
    const int b = bh >> 4, h = bh & 15;
    __shared__ __hip_bfloat16 t[64 * 66];
    const int tid = threadIdx.x;
#pragma unroll
    for (int i = 0; i < 16; ++i) {
        int idx = tid + i * 256;
        int lr = idx >> 6, d = idx & 63;
        t[lr * 66 + d] = qkv[(size_t)(b * LL + lt * 64 + lr) * 3072 + 2048 + h * 64 + d];
    }
    __syncthreads();
#pragma unroll
    for (int i = 0; i < 16; ++i) {
        int idx = tid + i * 256;
        int dr = idx >> 6, lc = idx & 63;
        vt[((size_t)bh * 64 + dr) * LL + lt * 64 + lc] = t[lc * 66 + dr];
    }
}

// ================= 256x256 8-phase GEMM (T2+T3+T4+T5) =================
// C[M,N] = A[M,K] x B^T[N,K], bf16 in, f32 acc. 512 thr = 8 waves (2M x 4N),
// per-wave 128x64 output (acc[8][4]). BK=64, double-buffered LDS halves,
// 4 phases/K-tile, 1 half-tile staged per phase, counted vmcnt(4) per tile.
// LDS layout per half-tile: [128 rows][8 slots][8 elems]; slot = chunk ^ (row&7)
// (XOR swizzle applied on the pre-swizzled GLOBAL source; reads use same XOR).
// MODE 0: bf16 out + 3-range bias (QKV). MODE 2: bf16 out + bias + relu.
template <int MODE>
__global__ __launch_bounds__(512, 2) void gemm256(
    const __hip_bfloat16* __restrict__ A, const __hip_bfloat16* __restrict__ Bm,
    int M, int N, int K, void* __restrict__ Cout,
    const float* __restrict__ bias0, const float* __restrict__ bias1,
    const float* __restrict__ bias2) {
    __shared__ __hip_bfloat16 lds[2][2][2][128 * 64]; // [buf][op A=0/B=1][half][r*64+e]
    const int m0 = blockIdx.x * 256, n0 = blockIdx.y * 256;
    const int tid = threadIdx.x;
    const int wid = tid >> 6, l = tid & 63;
    const int wm = wid >> 2, wn = wid & 3;
    const int lr = l & 15, lg = l >> 4;
    const int T = K >> 6;

    // staging coords: thread covers chunks c0=tid, c1=tid+512 of each half-tile
    const int c0 = tid, c1 = tid + 512;
    const int r0 = c0 >> 3, s0 = (((c0 & 7) ^ (r0 & 7)) << 3);
    const int r1 = c1 >> 3, s1 = (((c1 & 7) ^ (r1 & 7)) << 3);
    const int ldst0 = wid * 512;        // wave-uniform LDS elem offset, load 0
    const int ldst1 = 4096 + wid * 512; // load 1

#define STAGE(bi, isb, half, kt)                                                   \
    do {                                                                           \
        const __hip_bfloat16* _s = (isb) ? Bm : A;                                 \
        const int _br = ((isb) ? n0 : m0) + (half) * 128;                          \
        __hip_bfloat16* _d = &lds[bi][isb][half][0];                               \
        async_ld16(_s + (size_t)(_br + r0) * K + (kt) * 64 + s0, _d + ldst0);      \
        async_ld16(_s + (size_t)(_br + r1) * K + (kt) * 64 + s1, _d + ldst1);      \
    } while (0)

    f32x4 acc[8][4];
#pragma unroll
    for (int m = 0; m < 8; ++m)
#pragma unroll
        for (int n = 0; n < 4; ++n) acc[m][n] = (f32x4){0.f, 0.f, 0.f, 0.f};

    short8 aR[4][2], bR[4][2];

    // A frag read: wave's A-half = wm; local row = m*16+lr; chunk = kh*4+lg
#define LDA(dst, bi, m, kh)                                                        \
    do {                                                                           \
        const int _ra = (m) * 16 + lr;                                             \
        const int _sl = ((kh) * 4 + lg) ^ (_ra & 7);                               \
        dst = *reinterpret_cast<const short8*>(&lds[bi][0][wm][_ra * 64 + _sl * 8]); \
    } while (0)
    // B frag read: B-half = wn>>1; local row = (wn&1)*64 + n*16 + lr
#define LDB(dst, bi, n, kh)                                                        \
    do {                                                                           \
        const int _rb = (wn & 1) * 64 + (n) * 16 + lr;                             \
        const int _sl = ((kh) * 4 + lg) ^ (_rb & 7);                               \
        dst = *reinterpret_cast<const short8*>(&lds[bi][1][wn >> 1][_rb * 64 + _sl * 8]); \
    } while (0)

    // prologue: B0(0) A0(0) B1(0) A1(0) B0(1) A0(1)  (6 half-tiles, 12 loads)
    STAGE(0, 1, 0, 0);
    STAGE(0, 0, 0, 0);
    STAGE(0, 1, 1, 0);
    STAGE(0, 0, 1, 0);
    if (T > 1) {
        STAGE(1, 1, 0, 1);
        STAGE(1, 0, 0, 1);
        asm volatile("s_waitcnt vmcnt(4)" ::: "memory"); // tile 0 fully arrived
    } else {
        asm volatile("s_waitcnt vmcnt(0)" ::: "memory");
    }
    wg_barrier();

    for (int t = 0; t < T; ++t) {
        const int cur = t & 1, nxt = cur ^ 1;
        // ---- phase 0: quadrant (mh0, nh0); stage B1(t+1) ----
#pragma unroll
        for (int m = 0; m < 4; ++m) {
            LDA(aR[m][0], cur, m, 0);
            LDA(aR[m][1], cur, m, 1);
        }
#pragma unroll
        for (int n = 0; n < 2; ++n) {
            LDB(bR[n][0], cur, n, 0);
            LDB(bR[n][1], cur, n, 1);
        }
        if (t + 1 < T) STAGE(nxt, 1, 1, t + 1);
        wg_barrier();
        __builtin_amdgcn_s_setprio(1);
#pragma unroll
        for (int m = 0; m < 4; ++m)
#pragma unroll
            for (int n = 0; n < 2; ++n) {
                acc[m][n] = mfma16(aR[m][0], bR[n][0], acc[m][n]);
                acc[m][n] = mfma16(aR[m][1], bR[n][1], acc[m][n]);
            }
        __builtin_amdgcn_s_setprio(0);
        wg_barrier();
        // ---- phase 1: (mh0, nh1); stage A1(t+1) ----
#pragma unroll
        for (int n = 2; n < 4; ++n) {
            LDB(bR[n][0], cur, n, 0);
            LDB(bR[n][1], cur, n, 1);
        }
        if (t + 1 < T) STAGE(nxt, 0, 1, t + 1);
        wg_barrier();
        __builtin_amdgcn_s_setprio(1);
#pragma unroll
        for (int m = 0; m < 4; ++m)
#pragma unroll
            for (int n = 2; n < 4; ++n) {
                acc[m][n] = mfma16(aR[m][0], bR[n][0], acc[m][n]);
                acc[m][n] = mfma16(aR[m][1], bR[n][1], acc[m][n]);
            }
        __builtin_amdgcn_s_setprio(0);
        wg_barrier();
        // ---- phase 2: (mh1, nh0); stage B0(t+2) ----
#pragma unroll
        for (int m = 0; m < 4; ++m) {
            LDA(aR[m][0], cur, m + 4, 0);
            LDA(aR[m][1], cur, m + 4, 1);
        }
        if (t + 2 < T) STAGE(cur, 1, 0, t + 2);
        wg_barrier();
        __builtin_amdgcn_s_setprio(1);
#pragma unroll
        for (int m = 0; m < 4; ++m)
#pragma unroll
            for (int n = 0; n < 2; ++n) {
                acc[m + 4][n] = mfma16(aR[m][0], bR[n][0], acc[m + 4][n]);
                acc[m + 4][n] = mfma16(aR[m][1], bR[n][1], acc[m + 4][n]);
            }
        __builtin_amdgcn_s_setprio(0);
        wg_barrier();
        // ---- phase 3: (mh1, nh1); stage A0(t+2); counted vmcnt ----
        if (t + 2 < T) STAGE(cur, 0, 0, t + 2);
        wg_barrier();
        __builtin_amdgcn_s_setprio(1);
#pragma unroll
        for (int m = 0; m < 4; ++m)
#pragma unroll
            for (int n = 2; n < 4; ++n) {
                acc[m + 4][n] = mfma16(aR[m][0], bR[n][0], acc[m + 4][n]);
                acc[m + 4][n] = mfma16(aR[m][1], bR[n][1], acc[m + 4][n]);
            }
        __builtin_amdgcn_s_setprio(0);
        if (t + 2 < T)
            asm volatile("s_waitcnt vmcnt(4)" ::: "memory"); // tile t+1 arrived, 2 ht in flight
        else
            asm volatile("s_waitcnt vmcnt(0)" ::: "memory"); // epilogue drain
        wg_barrier();
    }
#undef STAGE
#undef LDA
#undef LDB

    // epilogue
#pragma unroll
    for (int n = 0; n < 4; ++n) {
        const int col = n0 + wn * 64 + n * 16 + lr;
        float bv;
        if constexpr (MODE == 0) {
            int s = col >> 10;
            const float* bp = (s == 0) ? bias0 : ((s == 1) ? bias1 : bias2);
            bv = bp[col & 1023];
        } else {
            bv = bias0[col];
        }
#pragma unroll
        for (int m = 0; m < 8; ++m) {
            const int row = m0 + wm * 128 + m * 16 + lg * 4;
#pragma unroll
            for (int r = 0; r < 4; ++r) {
                float v = acc[m][n][r] + bv;
                if constexpr (MODE == 2) v = fmaxf(v, 0.f);
                ((__hip_bfloat16*)Cout)[(size_t)(row + r) * N + col] = __float2bfloat16(v);
            }
        }
    }
}

// ---------------- GEMM: C[M,N] = A[M,K] (bf16) x B^T[N,K] (bf16), f32 acc ----------------
// m97-structure 128x128 (kept for N=1024 GEMMs). MODE 3: f32 out, bias.
template <int MODE>
__global__ __launch_bounds__(256) void gemm_bf16(
    const __hip_bfloat16* __restrict__ A, const __hip_bfloat16* __restrict__ Bm,
    int M, int N, int K, void* __restrict__ Cout,
    const float* __restrict__ bias0, const float* __restrict__ bias1,
    const float* __restrict__ bias2) {
    __shared__ __hip_bfloat16 As[128 * 32];
    __shared__ __hip_bfloat16 Bs[128 * 32];
    const int m0 = blockIdx.x * 128, n0 = blockIdx.y * 128;
    const int tid = threadIdx.x;
    const int w = tid >> 6, l = tid & 63;
    const int lr = l & 15, lg = l >> 4;
    const int wr = (w >> 1) * 64, wc = (w & 1) * 64;

    f32x4 acc[4][4];
#pragma unroll
    for (int m = 0; m < 4; ++m)
#pragma unroll
        for (int n = 0; n < 4; ++n) acc[m][n] = (f32x4){0.f, 0.f, 0.f, 0.f};

    const __hip_bfloat16* ga = A + (size_t)(m0 + w * 32 + (l >> 2)) * K + ((l & 3) << 3);
    const __hip_bfloat16* gb = Bm + (size_t)(n0 + w * 32 + (l >> 2)) * K + ((l & 3) << 3);
    const size_t row16 = (size_t)16 * K;
    __hip_bfloat16* lA0 = As + (w * 32) * 32;
    __hip_bfloat16* lA1 = As + (w * 32 + 16) * 32;
    __hip_bfloat16* lB0 = Bs + (w * 32) * 32;
    __hip_bfloat16* lB1 = Bs + (w * 32 + 16) * 32;

    for (int kt = 0; kt < K; kt += 32) {
        __syncthreads();
        async_ld16(ga + kt, lA0);
        async_ld16(ga + kt + row16, lA1);
        async_ld16(gb + kt, lB0);
        async_ld16(gb + kt + row16, lB1);
        __syncthreads();
        short8 af[4], bfr[4];
#pragma unroll
        for (int m = 0; m < 4; ++m)
            af[m] = *reinterpret_cast<const short8*>(As + (wr + m * 16 + lr) * 32 + lg * 8);
#pragma unroll
        for (int n = 0; n < 4; ++n)
            bfr[n] = *reinterpret_cast<const short8*>(Bs + (wc + n * 16 + lr) * 32 + lg * 8);
#pragma unroll
        for (int m = 0; m < 4; ++m)
#pragma unroll
            for (int n = 0; n < 4; ++n) acc[m][n] = mfma16(af[m], bfr[n], acc[m][n]);
    }

#pragma unroll
    for (int n = 0; n < 4; ++n) {
        const int col = n0 + wc + n * 16 + lr;
        float bv;
        if constexpr (MODE == 0) {
            int s = col >> 10;
            const float* bp = (s == 0) ? bias0 : ((s == 1) ? bias1 : bias2);
            bv = bp[col & 1023];
        } else {
            bv = bias0[col];
        }
#pragma unroll
        for (int m = 0; m < 4; ++m) {
            const int row = m0 + wr + m * 16 + lg * 4;
#pragma unroll
            for (int r = 0; r < 4; ++r) {
                float v = acc[m][n][r] + bv;
                if constexpr (MODE == 2) v = fmaxf(v, 0.f);
                if constexpr (MODE == 0 || MODE == 2) {
                    ((__hip_bfloat16*)Cout)[(size_t)(row + r) * N + col] = __float2bfloat16(v);
                } else {
                    ((float*)Cout)[(size_t)(row + r) * N + col] = v;
                }
            }
        }
    }
}

// ---------------- flash attention v2 ----------------
__global__ __launch_bounds__(256) void attn2(const __hip_bfloat16* __restrict__ qkv,
                                             const __hip_bfloat16* __restrict__ vt,
                                             __hip_bfloat16* __restrict__ cat) {
    const int qt = blockIdx.x, bh = blockIdx.y;
    const int b = bh >> 4, h = bh & 15;
    const int tid = threadIdx.x, w = tid >> 6, l = tid & 63;
    const int lr = l & 15, lg = l >> 4;

    __shared__ __hip_bfloat16 Ks[2][64 * 64]; // [kv][d], chunk-swizzled
    __shared__ __hip_bfloat16 Vs[2][64 * 64]; // [d][kv], chunk-swizzled
    __shared__ __hip_bfloat16 plds[4][16 * 72];

    const size_t qrow = (size_t)(b * LL + qt * 64 + w * 16 + lr);
    const short8 qa0 = *reinterpret_cast<const short8*>(qkv + qrow * 3072 + h * 64 + lg * 8);
    const short8 qa1 = *reinterpret_cast<const short8*>(qkv + qrow * 3072 + h * 64 + 32 + lg * 8);

    const int cA = w * 64 + l, cB = 256 + w * 64 + l;
    const int rA = cA >> 3, sA = (((cA & 7) ^ (rA & 7)) << 3);
    const int rB = cB >> 3, sB = (((cB & 7) ^ (rB & 7)) << 3);
    const __hip_bfloat16* kgA = qkv + (size_t)(b * LL + rA) * 3072 + 1024 + h * 64 + sA;
    const __hip_bfloat16* kgB = qkv + (size_t)(b * LL + rB) * 3072 + 1024 + h * 64 + sB;
    const __hip_bfloat16* vgA = vt + ((size_t)bh * 64 + rA) * LL + sA;
    const __hip_bfloat16* vgB = vt + ((size_t)bh * 64 + rB) * LL + sB;

#define STAGE_KV(bi, k0)                                                     \
    do {                                                                     \
        async_ld16(kgA + (size_t)(k0) * 3072, &Ks[bi][(w * 64) * 8]);        \
        async_ld16(kgB + (size_t)(k0) * 3072, &Ks[bi][(256 + w * 64) * 8]);  \
        async_ld16(vgA + (k0), &Vs[bi][(w * 64) * 8]);                       \
        async_ld16(vgB + (k0), &Vs[bi][(256 + w * 64) * 8]);                 \
    } while (0)

    float mrun[4], lrun[4];
    f32x4 oacc[4];
#pragma unroll
    for (int r = 0; r < 4; ++r) { mrun[r] = -INFINITY; lrun[r] = 0.f; }
#pragma unroll
    for (int n = 0; n < 4; ++n) oacc[n] = (f32x4){0.f, 0.f, 0.f, 0.f};

    STAGE_KV(0, 0);
    asm volatile("s_waitcnt vmcnt(0)" ::: "memory");
    __syncthreads();

    int cur = 0;
    for (int kt = 0; kt < 16; ++kt) {
        if (kt < 15) STAGE_KV(cur ^ 1, (kt + 1) * 64);

        f32x4 s[4];
#pragma unroll
        for (int n = 0; n < 4; ++n) {
            const int krow = n * 16 + lr;
            const int sw = krow & 7;
            const short8 kf0 =
                *reinterpret_cast<const short8*>(&Ks[cur][krow * 64 + ((lg ^ sw) << 3)]);
            const short8 kf1 =
                *reinterpret_cast<const short8*>(&Ks[cur][krow * 64 + (((lg + 4) ^ sw) << 3)]);
            f32x4 t = (f32x4){0.f, 0.f, 0.f, 0.f};
            t = mfma16(qa0, kf0, t);
            t = mfma16(qa1, kf1, t);
            s[n] = t * 0.125f;
        }
        float ps[4], alpha[4];
#pragma unroll
        for (int r = 0; r < 4; ++r) {
            float mx = fmaxf(fmaxf(s[0][r], s[1][r]), fmaxf(s[2][r], s[3][r]));
#pragma unroll
            for (int msk = 1; msk < 16; msk <<= 1) mx = fmaxf(mx, __shfl_xor(mx, msk, 64));
            float mnew = fmaxf(mrun[r], mx);
            alpha[r] = __expf(mrun[r] - mnew);
            mrun[r] = mnew;
            float p0 = 0.f;
#pragma unroll
            for (int n = 0; n < 4; ++n) {
                float p = __expf(s[n][r] - mnew);
                s[n][r] = p;
                p0 += p;
            }
#pragma unroll
            for (int msk = 1; msk < 16; msk <<= 1) p0 += __shfl_xor(p0, msk, 64);
            ps[r] = p0;
        }
#pragma unroll
        for (int r = 0; r < 4; ++r) lrun[r] = lrun[r] * alpha[r] + ps[r];
#pragma unroll
        for (int n = 0; n < 4; ++n)
#pragma unroll
            for (int r = 0; r < 4; ++r) oacc[n][r] *= alpha[r];

#pragma unroll
        for (int n = 0; n < 4; ++n)
#pragma unroll
            for (int r = 0; r < 4; ++r)
                plds[w][(lg * 4 + r) * 72 + n * 16 + lr] = __float2bfloat16(s[n][r]);
        asm volatile("s_waitcnt lgkmcnt(0)" ::: "memory");
        __builtin_amdgcn_sched_barrier(0);

        const short8 pa0 = *reinterpret_cast<const short8*>(&plds[w][lr * 72 + lg * 8]);
        const short8 pa1 = *reinterpret_cast<const short8*>(&plds[w][lr * 72 + 32 + lg * 8]);
#pragma unroll
        for (int n = 0; n < 4; ++n) {
            const int vrow = n * 16 + lr;
            const int sw = vrow & 7;
            const short8 vf0 =
                *reinterpret_cast<const short8*>(&Vs[cur][vrow * 64 + ((lg ^ sw) << 3)]);
            const short8 vf1 =
                *reinterpret_cast<const short8*>(&Vs[cur][vrow * 64 + (((lg + 4) ^ sw) << 3)]);
            oacc[n] = mfma16(pa0, vf0, oacc[n]);
            oacc[n] = mfma16(pa1, vf1, oacc[n]);
        }

        asm volatile("s_waitcnt vmcnt(0)" ::: "memory");
        __syncthreads();
        cur ^= 1;
    }
#undef STAGE_KV

#pragma unroll
    for (int n = 0; n < 4; ++n)
#pragma unroll
        for (int r = 0; r < 4; ++r) {
            float v = oacc[n][r] / lrun[r];
            cat[(size_t)(b * LL + qt * 64 + w * 16 + lg * 4 + r) * EE + h * 64 + n * 16 + lr] =
                __float2bfloat16(v);
        }
}

// ---------------- LayerNorm over E=1024 ----------------
__global__ __launch_bounds__(256) void ln_ker(const float* __restrict__ a,
                                              const float* __restrict__ b,
                                              const float* __restrict__ gamma,
                                              const float* __restrict__ beta,
                                              float* __restrict__ outf,
                                              __hip_bfloat16* __restrict__ outb) {
    const int row = blockIdx.x, tid = threadIdx.x;
    const size_t base = (size_t)row * EE;
    float4 x = reinterpret_cast<const float4*>(a + base)[tid];
    float4 y = reinterpret_cast<const float4*>(b + base)[tid];
    x.x += y.x; x.y += y.y; x.z += y.z; x.w += y.w;
    float s = x.x + x.y + x.z + x.w;
    float s2 = x.x * x.x + x.y * x.y + x.z * x.z + x.w * x.w;
#pragma unroll
    for (int msk = 1; msk < 64; msk <<= 1) {
        s += __shfl_xor(s, msk, 64);
        s2 += __shfl_xor(s2, msk, 64);
    }
    __shared__ float red[8];
    const int w = tid >> 6, l = tid & 63;
    if (l == 0) { red[w] = s; red[4 + w] = s2; }
    __syncthreads();
    s = red[0] + red[1] + red[2] + red[3];
    s2 = red[4] + red[5] + red[6] + red[7];
    const float mean = s * (1.f / 1024.f);
    const float var = s2 * (1.f / 1024.f) - mean * mean;
    const float rstd = rsqrtf(var + 1e-10f);
    float4 g = reinterpret_cast<const float4*>(gamma)[tid];
    float4 bt = reinterpret_cast<const float4*>(beta)[tid];
    float4 o;
    o.x = g.x * (x.x - mean) * rstd + bt.x;
    o.y = g.y * (x.y - mean) * rstd + bt.y;
    o.z = g.z * (x.z - mean) * rstd + bt.z;
    o.w = g.w * (x.w - mean) * rstd + bt.w;
    reinterpret_cast<float4*>(outf + base)[tid] = o;
    if (outb) {
        ushort4 ob;
        ob.x = bf16bits(o.x); ob.y = bf16bits(o.y); ob.z = bf16bits(o.z); ob.w = bf16bits(o.w);
        reinterpret_cast<ushort4*>(outb + base)[tid] = ob;
    }
}

extern "C" void kernel_launch(void* const* d_in, const int* in_sizes, int n_in,
                              void* d_out, int out_size, void* d_ws, size_t ws_size,
                              hipStream_t stream) {
    const float* x = (const float*)d_in[0];
    const float* Wq = (const float*)d_in[1];
    const float* bq = (const float*)d_in[2];
    const float* Wk = (const float*)d_in[3];
    const float* bk = (const float*)d_in[4];
    const float* Wv = (const float*)d_in[5];
    const float* bv = (const float*)d_in[6];
    const float* Wo = (const float*)d_in[7];
    const float* bo = (const float*)d_in[8];
    const float* W1 = (const float*)d_in[9];
    const float* b1 = (const float*)d_in[10];
    const float* W2 = (const float*)d_in[11];
    const float* b2 = (const float*)d_in[12];
    const float* gamma1 = (const float*)d_in[13];
    const float* beta1 = (const float*)d_in[14];
    const float* gamma2 = (const float*)d_in[15];
    const float* beta2 = (const float*)d_in[16];
    float* out = (float*)d_out;

    char* Wb = (char*)d_ws;
    const size_t MB = (size_t)1 << 20;
    if (ws_size < 168 * MB) return;
    __hip_bfloat16* xb = (__hip_bfloat16*)(Wb + 0 * MB);
    __hip_bfloat16* wqkvt = (__hip_bfloat16*)(Wb + 16 * MB);
    __hip_bfloat16* wot = (__hip_bfloat16*)(Wb + 22 * MB);
    __hip_bfloat16* w1t = (__hip_bfloat16*)(Wb + 24 * MB);
    __hip_bfloat16* w2t = (__hip_bfloat16*)(Wb + 32 * MB);
    __hip_bfloat16* qkvb = (__hip_bfloat16*)(Wb + 40 * MB);
    __hip_bfloat16* vtb = (__hip_bfloat16*)(Wb + 88 * MB);
    __hip_bfloat16* catb = (__hip_bfloat16*)(Wb + 104 * MB);
    float* out2f = (float*)(Wb + 120 * MB);
    __hip_bfloat16* out2b = (__hip_bfloat16*)(Wb + 152 * MB);
    __hip_bfloat16* hbuf = (__hip_bfloat16*)(Wb + 40 * MB); // reuses qkv+vt

    cvt_bf16<<<8192, 256, 0, stream>>>(x, xb);
    wtrans<<<dim3(16, 1, 16), 256, 0, stream>>>(Wq, wqkvt, 1024, 64, 65536, 65536);
    wtrans<<<dim3(16, 1, 16), 256, 0, stream>>>(Wk, wqkvt + 1024 * 1024, 1024, 64, 65536, 65536);
    wtrans<<<dim3(16, 1, 16), 256, 0, stream>>>(Wv, wqkvt + 2048 * 1024, 1024, 64, 65536, 65536);
    wtrans<<<dim3(16, 16, 1), 256, 0, stream>>>(Wo, wot, 1024, 1024, 0, 0);
    wtrans<<<dim3(16, 64, 1), 256, 0, stream>>>(W1, w1t, 1024, 4096, 0, 0);
    wtrans<<<dim3(64, 16, 1), 256, 0, stream>>>(W2, w2t, 4096, 1024, 0, 0);
    // QKV projection: 8-phase 256^2
    gemm256<0><<<dim3(32, 12), 512, 0, stream>>>(xb, wqkvt, 8192, 3072, 1024, qkvb, bq, bk, bv);
    vtrans<<<dim3(128, 16), 256, 0, stream>>>(qkvb, vtb);
    attn2<<<dim3(16, 128), 256, 0, stream>>>(qkvb, vtb, catb);
    // output projection (f32 into d_out as scratch)
    gemm_bf16<3><<<dim3(64, 8), 256, 0, stream>>>(catb, wot, 8192, 1024, 1024, out, bo, nullptr, nullptr);
    ln_ker<<<8192, 256, 0, stream>>>(out, x, gamma1, beta1, out2f, out2b);
    // FFN1 + ReLU: 8-phase 256^2
    gemm256<2><<<dim3(32, 16), 512, 0, stream>>>(out2b, w1t, 8192, 4096, 1024, hbuf, b1, nullptr, nullptr);
    gemm_bf16<3><<<dim3(64, 8), 256, 0, stream>>>(hbuf, w2t, 8192, 1024, 4096, out, b2, nullptr, nullptr);
    ln_ker<<<8192, 256, 0, stream>>>(out, out2f, gamma2, beta2, out, nullptr);
}

// Round 4
// 417.812 us; speedup vs baseline: 1.4104x; 1.1308x over previous
//
#include <hip/hip_runtime.h>
#include <hip/hip_bf16.h>

// Shapes (fixed per reference)
#define BB 8
#define LL 1024
#define EE 1024
#define HH 16
#define DHH 64
#define FFF 4096

typedef __attribute__((ext_vector_type(8))) short short8;
typedef __attribute__((ext_vector_type(4))) float f32x4;

__device__ inline f32x4 mfma16(short8 a, short8 b, f32x4 c) {
    return __builtin_amdgcn_mfma_f32_16x16x32_bf16(a, b, c, 0, 0, 0);
}

__device__ inline void async_ld16(const __hip_bfloat16* g, __hip_bfloat16* l) {
    __builtin_amdgcn_global_load_lds(
        (const __attribute__((address_space(1))) void*)g,
        (__attribute__((address_space(3))) void*)l, 16, 0, 0);
}

__device__ inline unsigned short bf16bits(float f) {
    __hip_bfloat16 h = __float2bfloat16(f);
    return *reinterpret_cast<unsigned short*>(&h);
}

__device__ inline float exp2_fast(float x) {
    float r;
    asm("v_exp_f32 %0, %1" : "=v"(r) : "v"(x));
    return r;
}

__device__ inline unsigned cvt_pk_bf16(float lo, float hi) {
    unsigned r;
    asm("v_cvt_pk_bf16_f32 %0, %1, %2" : "=v"(r) : "v"(lo), "v"(hi));
    return r;
}

// raw workgroup barrier (no implicit vmcnt(0) drain), with compiler memory fence
__device__ inline void wg_barrier() {
    asm volatile("" ::: "memory");
    __builtin_amdgcn_s_barrier();
    asm volatile("" ::: "memory");
}

// ---------------- elementwise f32 -> bf16 ----------------
__global__ __launch_bounds__(256) void cvt_bf16(const float* __restrict__ in,
                                                __hip_bfloat16* __restrict__ out) {
    size_t i = (size_t)blockIdx.x * 256 + threadIdx.x; // one float4 per thread
    float4 v = reinterpret_cast<const float4*>(in)[i];
    ushort4 o;
    o.x = bf16bits(v.x); o.y = bf16bits(v.y); o.z = bf16bits(v.z); o.w = bf16bits(v.w);
    reinterpret_cast<ushort4*>(out)[i] = o;
}

// ---------------- weight transpose+convert: dst[n*K+k] = src[k*N+n] ----------------
__global__ __launch_bounds__(256) void wtrans(const float* __restrict__ src,
                                              __hip_bfloat16* __restrict__ dst,
                                              int K, int N, long src_z, long dst_z) {
    src += (size_t)blockIdx.z * src_z;
    dst += (size_t)blockIdx.z * dst_z;
    __shared__ __hip_bfloat16 t[64 * 66]; // pad 66: strided phase conflict-free
    const int k0 = blockIdx.x * 64, n0 = blockIdx.y * 64;
    const int tid = threadIdx.x;
#pragma unroll
    for (int i = 0; i < 16; ++i) {
        int idx = tid + i * 256;
        int kr = idx >> 6, nc = idx & 63;
        t[kr * 66 + nc] = __float2bfloat16(src[(size_t)(k0 + kr) * N + n0 + nc]);
    }
    __syncthreads();
#pragma unroll
    for (int i = 0; i < 16; ++i) {
        int idx = tid + i * 256;
        int nr = idx >> 6, kc = idx & 63;
        dst[(size_t)(n0 + nr) * K + k0 + kc] = t[kc * 66 + nr];
    }
}

// ---------------- V transpose: qkv cols [2048..3072) -> vt[(b,h,d)][l] ----------------
__global__ __launch_bounds__(256) void vtrans(const __hip_bfloat16* __restrict__ qkv,
                                              __hip_bfloat16* __restrict__ vt) {
    const int bh = blockIdx.x, lt = blockIdx.y;
    const int b = bh >> 4, h = bh & 15;
    __shared__ __hip_bfloat16 t[64 * 66];
    const int tid = threadIdx.x;
#pragma unroll
    for (int i = 0; i < 16; ++i) {
        int idx = tid + i * 256;
        int lr = idx >> 6, d = idx & 63;
        t[lr * 66 + d] = qkv[(size_t)(b * LL + lt * 64 + lr) * 3072 + 2048 + h * 64 + d];
    }
    __syncthreads();
#pragma unroll
    for (int i = 0; i < 16; ++i) {
        int idx = tid + i * 256;
        int dr = idx >> 6, lc = idx & 63;
        vt[((size_t)bh * 64 + dr) * LL + lt * 64 + lc] = t[lc * 66 + dr];
    }
}

// ================= 256x256 8-phase GEMM (T2+T3+T4+T5) =================
template <int MODE>
__global__ __launch_bounds__(512, 2) void gemm256(
    const __hip_bfloat16* __restrict__ A, const __hip_bfloat16* __restrict__ Bm,
    int M, int N, int K, void* __restrict__ Cout,
    const float* __restrict__ bias0, const float* __restrict__ bias1,
    const float* __restrict__ bias2) {
    __shared__ __hip_bfloat16 lds[2][2][2][128 * 64]; // [buf][op A=0/B=1][half][r*64+e]
    const int m0 = blockIdx.x * 256, n0 = blockIdx.y * 256;
    const int tid = threadIdx.x;
    const int wid = tid >> 6, l = tid & 63;
    const int wm = wid >> 2, wn = wid & 3;
    const int lr = l & 15, lg = l >> 4;
    const int T = K >> 6;

    const int c0 = tid, c1 = tid + 512;
    const int r0 = c0 >> 3, s0 = (((c0 & 7) ^ (r0 & 7)) << 3);
    const int r1 = c1 >> 3, s1 = (((c1 & 7) ^ (r1 & 7)) << 3);
    const int ldst0 = wid * 512;
    const int ldst1 = 4096 + wid * 512;

#define STAGE(bi, isb, half, kt)                                                   \
    do {                                                                           \
        const __hip_bfloat16* _s = (isb) ? Bm : A;                                 \
        const int _br = ((isb) ? n0 : m0) + (half) * 128;                          \
        __hip_bfloat16* _d = &lds[bi][isb][half][0];                               \
        async_ld16(_s + (size_t)(_br + r0) * K + (kt) * 64 + s0, _d + ldst0);      \
        async_ld16(_s + (size_t)(_br + r1) * K + (kt) * 64 + s1, _d + ldst1);      \
    } while (0)

    f32x4 acc[8][4];
#pragma unroll
    for (int m = 0; m < 8; ++m)
#pragma unroll
        for (int n = 0; n < 4; ++n) acc[m][n] = (f32x4){0.f, 0.f, 0.f, 0.f};

    short8 aR[4][2], bR[4][2];

#define LDA(dst, bi, m, kh)                                                        \
    do {                                                                           \
        const int _ra = (m) * 16 + lr;                                             \
        const int _sl = ((kh) * 4 + lg) ^ (_ra & 7);                               \
        dst = *reinterpret_cast<const short8*>(&lds[bi][0][wm][_ra * 64 + _sl * 8]); \
    } while (0)
#define LDB(dst, bi, n, kh)                                                        \
    do {                                                                           \
        const int _rb = (wn & 1) * 64 + (n) * 16 + lr;                             \
        const int _sl = ((kh) * 4 + lg) ^ (_rb & 7);                               \
        dst = *reinterpret_cast<const short8*>(&lds[bi][1][wn >> 1][_rb * 64 + _sl * 8]); \
    } while (0)

    STAGE(0, 1, 0, 0);
    STAGE(0, 0, 0, 0);
    STAGE(0, 1, 1, 0);
    STAGE(0, 0, 1, 0);
    if (T > 1) {
        STAGE(1, 1, 0, 1);
        STAGE(1, 0, 0, 1);
        asm volatile("s_waitcnt vmcnt(4)" ::: "memory");
    } else {
        asm volatile("s_waitcnt vmcnt(0)" ::: "memory");
    }
    wg_barrier();

    for (int t = 0; t < T; ++t) {
        const int cur = t & 1, nxt = cur ^ 1;
#pragma unroll
        for (int m = 0; m < 4; ++m) {
            LDA(aR[m][0], cur, m, 0);
            LDA(aR[m][1], cur, m, 1);
        }
#pragma unroll
        for (int n = 0; n < 2; ++n) {
            LDB(bR[n][0], cur, n, 0);
            LDB(bR[n][1], cur, n, 1);
        }
        if (t + 1 < T) STAGE(nxt, 1, 1, t + 1);
        wg_barrier();
        __builtin_amdgcn_s_setprio(1);
#pragma unroll
        for (int m = 0; m < 4; ++m)
#pragma unroll
            for (int n = 0; n < 2; ++n) {
                acc[m][n] = mfma16(aR[m][0], bR[n][0], acc[m][n]);
                acc[m][n] = mfma16(aR[m][1], bR[n][1], acc[m][n]);
            }
        __builtin_amdgcn_s_setprio(0);
        wg_barrier();
#pragma unroll
        for (int n = 2; n < 4; ++n) {
            LDB(bR[n][0], cur, n, 0);
            LDB(bR[n][1], cur, n, 1);
        }
        if (t + 1 < T) STAGE(nxt, 0, 1, t + 1);
        wg_barrier();
        __builtin_amdgcn_s_setprio(1);
#pragma unroll
        for (int m = 0; m < 4; ++m)
#pragma unroll
            for (int n = 2; n < 4; ++n) {
                acc[m][n] = mfma16(aR[m][0], bR[n][0], acc[m][n]);
                acc[m][n] = mfma16(aR[m][1], bR[n][1], acc[m][n]);
            }
        __builtin_amdgcn_s_setprio(0);
        wg_barrier();
#pragma unroll
        for (int m = 0; m < 4; ++m) {
            LDA(aR[m][0], cur, m + 4, 0);
            LDA(aR[m][1], cur, m + 4, 1);
        }
        if (t + 2 < T) STAGE(cur, 1, 0, t + 2);
        wg_barrier();
        __builtin_amdgcn_s_setprio(1);
#pragma unroll
        for (int m = 0; m < 4; ++m)
#pragma unroll
            for (int n = 0; n < 2; ++n) {
                acc[m + 4][n] = mfma16(aR[m][0], bR[n][0], acc[m + 4][n]);
                acc[m + 4][n] = mfma16(aR[m][1], bR[n][1], acc[m + 4][n]);
            }
        __builtin_amdgcn_s_setprio(0);
        wg_barrier();
        if (t + 2 < T) STAGE(cur, 0, 0, t + 2);
        wg_barrier();
        __builtin_amdgcn_s_setprio(1);
#pragma unroll
        for (int m = 0; m < 4; ++m)
#pragma unroll
            for (int n = 2; n < 4; ++n) {
                acc[m + 4][n] = mfma16(aR[m][0], bR[n][0], acc[m + 4][n]);
                acc[m + 4][n] = mfma16(aR[m][1], bR[n][1], acc[m + 4][n]);
            }
        __builtin_amdgcn_s_setprio(0);
        if (t + 2 < T)
            asm volatile("s_waitcnt vmcnt(4)" ::: "memory");
        else
            asm volatile("s_waitcnt vmcnt(0)" ::: "memory");
        wg_barrier();
    }
#undef STAGE
#undef LDA
#undef LDB

#pragma unroll
    for (int n = 0; n < 4; ++n) {
        const int col = n0 + wn * 64 + n * 16 + lr;
        float bv;
        if constexpr (MODE == 0) {
            int s = col >> 10;
            const float* bp = (s == 0) ? bias0 : ((s == 1) ? bias1 : bias2);
            bv = bp[col & 1023];
        } else {
            bv = bias0[col];
        }
#pragma unroll
        for (int m = 0; m < 8; ++m) {
            const int row = m0 + wm * 128 + m * 16 + lg * 4;
#pragma unroll
            for (int r = 0; r < 4; ++r) {
                float v = acc[m][n][r] + bv;
                if constexpr (MODE == 2) v = fmaxf(v, 0.f);
                ((__hip_bfloat16*)Cout)[(size_t)(row + r) * N + col] = __float2bfloat16(v);
            }
        }
    }
}

// ---------------- m97-structure 128x128 GEMM (N=1024 GEMMs). MODE 3: f32 out ----------------
template <int MODE>
__global__ __launch_bounds__(256) void gemm_bf16(
    const __hip_bfloat16* __restrict__ A, const __hip_bfloat16* __restrict__ Bm,
    int M, int N, int K, void* __restrict__ Cout,
    const float* __restrict__ bias0, const float* __restrict__ bias1,
    const float* __restrict__ bias2) {
    __shared__ __hip_bfloat16 As[128 * 32];
    __shared__ __hip_bfloat16 Bs[128 * 32];
    const int m0 = blockIdx.x * 128, n0 = blockIdx.y * 128;
    const int tid = threadIdx.x;
    const int w = tid >> 6, l = tid & 63;
    const int lr = l & 15, lg = l >> 4;
    const int wr = (w >> 1) * 64, wc = (w & 1) * 64;

    f32x4 acc[4][4];
#pragma unroll
    for (int m = 0; m < 4; ++m)
#pragma unroll
        for (int n = 0; n < 4; ++n) acc[m][n] = (f32x4){0.f, 0.f, 0.f, 0.f};

    const __hip_bfloat16* ga = A + (size_t)(m0 + w * 32 + (l >> 2)) * K + ((l & 3) << 3);
    const __hip_bfloat16* gb = Bm + (size_t)(n0 + w * 32 + (l >> 2)) * K + ((l & 3) << 3);
    const size_t row16 = (size_t)16 * K;
    __hip_bfloat16* lA0 = As + (w * 32) * 32;
    __hip_bfloat16* lA1 = As + (w * 32 + 16) * 32;
    __hip_bfloat16* lB0 = Bs + (w * 32) * 32;
    __hip_bfloat16* lB1 = Bs + (w * 32 + 16) * 32;

    for (int kt = 0; kt < K; kt += 32) {
        __syncthreads();
        async_ld16(ga + kt, lA0);
        async_ld16(ga + kt + row16, lA1);
        async_ld16(gb + kt, lB0);
        async_ld16(gb + kt + row16, lB1);
        __syncthreads();
        short8 af[4], bfr[4];
#pragma unroll
        for (int m = 0; m < 4; ++m)
            af[m] = *reinterpret_cast<const short8*>(As + (wr + m * 16 + lr) * 32 + lg * 8);
#pragma unroll
        for (int n = 0; n < 4; ++n)
            bfr[n] = *reinterpret_cast<const short8*>(Bs + (wc + n * 16 + lr) * 32 + lg * 8);
#pragma unroll
        for (int m = 0; m < 4; ++m)
#pragma unroll
            for (int n = 0; n < 4; ++n) acc[m][n] = mfma16(af[m], bfr[n], acc[m][n]);
    }

#pragma unroll
    for (int n = 0; n < 4; ++n) {
        const int col = n0 + wc + n * 16 + lr;
        float bv;
        if constexpr (MODE == 0) {
            int s = col >> 10;
            const float* bp = (s == 0) ? bias0 : ((s == 1) ? bias1 : bias2);
            bv = bp[col & 1023];
        } else {
            bv = bias0[col];
        }
#pragma unroll
        for (int m = 0; m < 4; ++m) {
            const int row = m0 + wr + m * 16 + lg * 4;
#pragma unroll
            for (int r = 0; r < 4; ++r) {
                float v = acc[m][n][r] + bv;
                if constexpr (MODE == 2) v = fmaxf(v, 0.f);
                if constexpr (MODE == 0 || MODE == 2) {
                    ((__hip_bfloat16*)Cout)[(size_t)(row + r) * N + col] = __float2bfloat16(v);
                } else {
                    ((float*)Cout)[(size_t)(row + r) * N + col] = v;
                }
            }
        }
    }
}

// ---------------- flash attention v3: swapped QK^T, in-register softmax ----------------
// 512 thr = 8 waves x 16 q-rows = 128 q-rows per block. KV tiles of 64, dbuf LDS.
// Swapped QK^T: mfma(K,Q) -> lane owns q = lane&15; 16 k-values in regs.
// Row reduce: 15 in-reg ops + 2 shfl_xor (16/32). Defer-max THR=8 (log2 domain).
// P packed via v_cvt_pk_bf16_f32 -> 4x ds_write_b64 per tile.
__global__ __launch_bounds__(512) void attn3(const __hip_bfloat16* __restrict__ qkv,
                                             const __hip_bfloat16* __restrict__ vt,
                                             __hip_bfloat16* __restrict__ cat) {
    const int qt = blockIdx.x, bh = blockIdx.y;
    const int b = bh >> 4, h = bh & 15;
    const int tid = threadIdx.x, w = tid >> 6, l = tid & 63;
    const int lr = l & 15, lg = l >> 4;
    const int sw = lr & 7; // row-XOR swizzle term for K/V fragment reads

    __shared__ __hip_bfloat16 Ks[2][64 * 64];   // [kv][d], chunk-swizzled
    __shared__ __hip_bfloat16 Vs[2][64 * 64];   // [d][kv], chunk-swizzled
    __shared__ __hip_bfloat16 plds[8][16 * 72]; // per-wave P transpose, pad 72

    // Q fragments: q = lr (one row per lane), d = lg*8..
    const size_t qrow = (size_t)(b * LL + qt * 128 + w * 16 + lr);
    const short8 qa0 = *reinterpret_cast<const short8*>(qkv + qrow * 3072 + h * 64 + lg * 8);
    const short8 qa1 = *reinterpret_cast<const short8*>(qkv + qrow * 3072 + h * 64 + 32 + lg * 8);

    // staging: 512 chunks/tile each for K and V; thread t -> chunk t.
    const int rA = tid >> 3, sA = (((tid & 7) ^ (rA & 7)) << 3);
    const __hip_bfloat16* kg = qkv + (size_t)(b * LL + rA) * 3072 + 1024 + h * 64 + sA;
    const __hip_bfloat16* vg = vt + ((size_t)bh * 64 + rA) * LL + sA;

#define STAGE_KV(bi, k0)                                      \
    do {                                                      \
        async_ld16(kg + (size_t)(k0) * 3072, &Ks[bi][w * 512]); \
        async_ld16(vg + (k0), &Vs[bi][w * 512]);              \
    } while (0)

    float mrun = -INFINITY, lrun = 0.f;
    f32x4 oacc[4];
#pragma unroll
    for (int n = 0; n < 4; ++n) oacc[n] = (f32x4){0.f, 0.f, 0.f, 0.f};

    STAGE_KV(0, 0);
    asm volatile("s_waitcnt vmcnt(0)" ::: "memory");
    __syncthreads();

    const float SCALE = 0.18033688011112042f; // 1/sqrt(64) * log2(e)

    int cur = 0;
    for (int kt = 0; kt < 16; ++kt) {
        if (kt < 15) STAGE_KV(cur ^ 1, (kt + 1) * 64);

        // swapped QK^T: s[m][r] = S_log2[k = m*16 + lg*4 + r][q = lr]
        f32x4 s[4];
#pragma unroll
        for (int m = 0; m < 4; ++m) {
            const int krow = m * 16 + lr;
            const short8 kf0 =
                *reinterpret_cast<const short8*>(&Ks[cur][krow * 64 + ((lg ^ sw) << 3)]);
            const short8 kf1 =
                *reinterpret_cast<const short8*>(&Ks[cur][krow * 64 + (((lg + 4) ^ sw) << 3)]);
            f32x4 t = (f32x4){0.f, 0.f, 0.f, 0.f};
            t = mfma16(kf0, qa0, t);
            t = mfma16(kf1, qa1, t);
            s[m] = t * SCALE;
        }
        // per-lane row max (q = lr)
        float smax = s[0][0];
#pragma unroll
        for (int m = 0; m < 4; ++m)
#pragma unroll
            for (int r = 0; r < 4; ++r) smax = fmaxf(smax, s[m][r]);
        smax = fmaxf(smax, __shfl_xor(smax, 16, 64));
        smax = fmaxf(smax, __shfl_xor(smax, 32, 64));
        // defer-max: rescale only when the running max grew by > 8 (log2)
        if (__any(smax > mrun + 8.0f)) {
            const float mnew = fmaxf(mrun, smax);
            const float alpha = exp2_fast(mrun - mnew);
            mrun = mnew;
            lrun *= alpha;
#pragma unroll
            for (int r = 0; r < 4; ++r) {
                const float aD = __shfl(alpha, lg * 4 + r, 64);
#pragma unroll
                for (int n = 0; n < 4; ++n) oacc[n][r] *= aD;
            }
        }
        // P = exp2(s - m), row sum
        float p[4][4];
        float tsum = 0.f;
#pragma unroll
        for (int m = 0; m < 4; ++m)
#pragma unroll
            for (int r = 0; r < 4; ++r) {
                p[m][r] = exp2_fast(s[m][r] - mrun);
                tsum += p[m][r];
            }
        tsum += __shfl_xor(tsum, 16, 64);
        tsum += __shfl_xor(tsum, 32, 64);
        lrun += tsum;

        // pack P -> plds[w][q=lr][k], 8B per m-block
#pragma unroll
        for (int m = 0; m < 4; ++m) {
            uint2 d;
            d.x = cvt_pk_bf16(p[m][0], p[m][1]);
            d.y = cvt_pk_bf16(p[m][2], p[m][3]);
            *reinterpret_cast<uint2*>(&plds[w][lr * 72 + m * 16 + lg * 4]) = d;
        }
        asm volatile("s_waitcnt lgkmcnt(0)" ::: "memory");
        __builtin_amdgcn_sched_barrier(0);

        const short8 pa0 = *reinterpret_cast<const short8*>(&plds[w][lr * 72 + lg * 8]);
        const short8 pa1 = *reinterpret_cast<const short8*>(&plds[w][lr * 72 + 32 + lg * 8]);
#pragma unroll
        for (int n = 0; n < 4; ++n) {
            const int vrow = n * 16 + lr;
            const short8 vf0 =
                *reinterpret_cast<const short8*>(&Vs[cur][vrow * 64 + ((lg ^ sw) << 3)]);
            const short8 vf1 =
                *reinterpret_cast<const short8*>(&Vs[cur][vrow * 64 + (((lg + 4) ^ sw) << 3)]);
            oacc[n] = mfma16(pa0, vf0, oacc[n]);
            oacc[n] = mfma16(pa1, vf1, oacc[n]);
        }

        asm volatile("s_waitcnt vmcnt(0)" ::: "memory");
        __syncthreads();
        cur ^= 1;
    }
#undef STAGE_KV

    // epilogue: divide by row sum (fetch lrun for q = lg*4+r from lane lg*4+r)
    float rinv[4];
#pragma unroll
    for (int r = 0; r < 4; ++r) rinv[r] = 1.0f / __shfl(lrun, lg * 4 + r, 64);
#pragma unroll
    for (int n = 0; n < 4; ++n)
#pragma unroll
        for (int r = 0; r < 4; ++r) {
            const float v = oacc[n][r] * rinv[r];
            cat[(size_t)(b * LL + qt * 128 + w * 16 + lg * 4 + r) * EE + h * 64 + n * 16 + lr] =
                __float2bfloat16(v);
        }
}

// ---------------- LayerNorm over E=1024 ----------------
__global__ __launch_bounds__(256) void ln_ker(const float* __restrict__ a,
                                              const float* __restrict__ b,
                                              const float* __restrict__ gamma,
                                              const float* __restrict__ beta,
                                              float* __restrict__ outf,
                                              __hip_bfloat16* __restrict__ outb) {
    const int row = blockIdx.x, tid = threadIdx.x;
    const size_t base = (size_t)row * EE;
    float4 x = reinterpret_cast<const float4*>(a + base)[tid];
    float4 y = reinterpret_cast<const float4*>(b + base)[tid];
    x.x += y.x; x.y += y.y; x.z += y.z; x.w += y.w;
    float s = x.x + x.y + x.z + x.w;
    float s2 = x.x * x.x + x.y * x.y + x.z * x.z + x.w * x.w;
#pragma unroll
    for (int msk = 1; msk < 64; msk <<= 1) {
        s += __shfl_xor(s, msk, 64);
        s2 += __shfl_xor(s2, msk, 64);
    }
    __shared__ float red[8];
    const int w = tid >> 6, l = tid & 63;
    if (l == 0) { red[w] = s; red[4 + w] = s2; }
    __syncthreads();
    s = red[0] + red[1] + red[2] + red[3];
    s2 = red[4] + red[5] + red[6] + red[7];
    const float mean = s * (1.f / 1024.f);
    const float var = s2 * (1.f / 1024.f) - mean * mean;
    const float rstd = rsqrtf(var + 1e-10f);
    float4 g = reinterpret_cast<const float4*>(gamma)[tid];
    float4 bt = reinterpret_cast<const float4*>(beta)[tid];
    float4 o;
    o.x = g.x * (x.x - mean) * rstd + bt.x;
    o.y = g.y * (x.y - mean) * rstd + bt.y;
    o.z = g.z * (x.z - mean) * rstd + bt.z;
    o.w = g.w * (x.w - mean) * rstd + bt.w;
    reinterpret_cast<float4*>(outf + base)[tid] = o;
    if (outb) {
        ushort4 ob;
        ob.x = bf16bits(o.x); ob.y = bf16bits(o.y); ob.z = bf16bits(o.z); ob.w = bf16bits(o.w);
        reinterpret_cast<ushort4*>(outb + base)[tid] = ob;
    }
}

extern "C" void kernel_launch(void* const* d_in, const int* in_sizes, int n_in,
                              void* d_out, int out_size, void* d_ws, size_t ws_size,
                              hipStream_t stream) {
    const float* x = (const float*)d_in[0];
    const float* Wq = (const float*)d_in[1];
    const float* bq = (const float*)d_in[2];
    const float* Wk = (const float*)d_in[3];
    const float* bk = (const float*)d_in[4];
    const float* Wv = (const float*)d_in[5];
    const float* bv = (const float*)d_in[6];
    const float* Wo = (const float*)d_in[7];
    const float* bo = (const float*)d_in[8];
    const float* W1 = (const float*)d_in[9];
    const float* b1 = (const float*)d_in[10];
    const float* W2 = (const float*)d_in[11];
    const float* b2 = (const float*)d_in[12];
    const float* gamma1 = (const float*)d_in[13];
    const float* beta1 = (const float*)d_in[14];
    const float* gamma2 = (const float*)d_in[15];
    const float* beta2 = (const float*)d_in[16];
    float* out = (float*)d_out;

    char* Wb = (char*)d_ws;
    const size_t MB = (size_t)1 << 20;
    if (ws_size < 168 * MB) return;
    __hip_bfloat16* xb = (__hip_bfloat16*)(Wb + 0 * MB);
    __hip_bfloat16* wqkvt = (__hip_bfloat16*)(Wb + 16 * MB);
    __hip_bfloat16* wot = (__hip_bfloat16*)(Wb + 22 * MB);
    __hip_bfloat16* w1t = (__hip_bfloat16*)(Wb + 24 * MB);
    __hip_bfloat16* w2t = (__hip_bfloat16*)(Wb + 32 * MB);
    __hip_bfloat16* qkvb = (__hip_bfloat16*)(Wb + 40 * MB);
    __hip_bfloat16* vtb = (__hip_bfloat16*)(Wb + 88 * MB);
    __hip_bfloat16* catb = (__hip_bfloat16*)(Wb + 104 * MB);
    float* out2f = (float*)(Wb + 120 * MB);
    __hip_bfloat16* out2b = (__hip_bfloat16*)(Wb + 152 * MB);
    __hip_bfloat16* hbuf = (__hip_bfloat16*)(Wb + 40 * MB); // reuses qkv+vt

    cvt_bf16<<<8192, 256, 0, stream>>>(x, xb);
    wtrans<<<dim3(16, 1, 16), 256, 0, stream>>>(Wq, wqkvt, 1024, 64, 65536, 65536);
    wtrans<<<dim3(16, 1, 16), 256, 0, stream>>>(Wk, wqkvt + 1024 * 1024, 1024, 64, 65536, 65536);
    wtrans<<<dim3(16, 1, 16), 256, 0, stream>>>(Wv, wqkvt + 2048 * 1024, 1024, 64, 65536, 65536);
    wtrans<<<dim3(16, 16, 1), 256, 0, stream>>>(Wo, wot, 1024, 1024, 0, 0);
    wtrans<<<dim3(16, 64, 1), 256, 0, stream>>>(W1, w1t, 1024, 4096, 0, 0);
    wtrans<<<dim3(64, 16, 1), 256, 0, stream>>>(W2, w2t, 4096, 1024, 0, 0);
    // QKV projection: 8-phase 256^2
    gemm256<0><<<dim3(32, 12), 512, 0, stream>>>(xb, wqkvt, 8192, 3072, 1024, qkvb, bq, bk, bv);
    vtrans<<<dim3(128, 16), 256, 0, stream>>>(qkvb, vtb);
    // attention v3: 128 q-rows/block, swapped QK^T, in-register softmax
    attn3<<<dim3(8, 128), 512, 0, stream>>>(qkvb, vtb, catb);
    // output projection (f32 into d_out as scratch)
    gemm_bf16<3><<<dim3(64, 8), 256, 0, stream>>>(catb, wot, 8192, 1024, 1024, out, bo, nullptr, nullptr);
    ln_ker<<<8192, 256, 0, stream>>>(out, x, gamma1, beta1, out2f, out2b);
    // FFN1 + ReLU: 8-phase 256^2
    gemm256<2><<<dim3(32, 16), 512, 0, stream>>>(out2b, w1t, 8192, 4096, 1024, hbuf, b1, nullptr, nullptr);
    gemm_bf16<3><<<dim3(64, 8), 256, 0, stream>>>(hbuf, w2t, 8192, 1024, 4096, out, b2, nullptr, nullptr);
    ln_ker<<<8192, 256, 0, stream>>>(out, out2f, gamma2, beta2, out, nullptr);
}

// Round 5
// 389.476 us; speedup vs baseline: 1.5130x; 1.0728x over previous
//
#include <hip/hip_runtime.h>
#include <hip/hip_bf16.h>

// Shapes (fixed per reference)
#define BB 8
#define LL 1024
#define EE 1024
#define HH 16
#define DHH 64
#define FFF 4096

typedef __attribute__((ext_vector_type(8))) short short8;
typedef __attribute__((ext_vector_type(4))) float f32x4;

__device__ inline f32x4 mfma16(short8 a, short8 b, f32x4 c) {
    return __builtin_amdgcn_mfma_f32_16x16x32_bf16(a, b, c, 0, 0, 0);
}

__device__ inline void async_ld16(const __hip_bfloat16* g, __hip_bfloat16* l) {
    __builtin_amdgcn_global_load_lds(
        (const __attribute__((address_space(1))) void*)g,
        (__attribute__((address_space(3))) void*)l, 16, 0, 0);
}

__device__ inline unsigned short bf16bits(float f) {
    __hip_bfloat16 h = __float2bfloat16(f);
    return *reinterpret_cast<unsigned short*>(&h);
}

__device__ inline float exp2_fast(float x) {
    float r;
    asm("v_exp_f32 %0, %1" : "=v"(r) : "v"(x));
    return r;
}

__device__ inline unsigned cvt_pk_bf16(float lo, float hi) {
    unsigned r;
    asm("v_cvt_pk_bf16_f32 %0, %1, %2" : "=v"(r) : "v"(lo), "v"(hi));
    return r;
}

// raw workgroup barrier (no implicit vmcnt(0) drain), with compiler memory fence
__device__ inline void wg_barrier() {
    asm volatile("" ::: "memory");
    __builtin_amdgcn_s_barrier();
    asm volatile("" ::: "memory");
}

// ---------------- elementwise f32 -> bf16 ----------------
__global__ __launch_bounds__(256) void cvt_bf16(const float* __restrict__ in,
                                                __hip_bfloat16* __restrict__ out) {
    size_t i = (size_t)blockIdx.x * 256 + threadIdx.x; // one float4 per thread
    float4 v = reinterpret_cast<const float4*>(in)[i];
    ushort4 o;
    o.x = bf16bits(v.x); o.y = bf16bits(v.y); o.z = bf16bits(v.z); o.w = bf16bits(v.w);
    reinterpret_cast<ushort4*>(out)[i] = o;
}

// ---------------- weight transpose+convert: dst[n*K+k] = src[k*N+n] ----------------
__global__ __launch_bounds__(256) void wtrans(const float* __restrict__ src,
                                              __hip_bfloat16* __restrict__ dst,
                                              int K, int N, long src_z, long dst_z) {
    src += (size_t)blockIdx.z * src_z;
    dst += (size_t)blockIdx.z * dst_z;
    __shared__ __hip_bfloat16 t[64 * 66]; // pad 66: strided phase conflict-free
    const int k0 = blockIdx.x * 64, n0 = blockIdx.y * 64;
    const int tid = threadIdx.x;
#pragma unroll
    for (int i = 0; i < 16; ++i) {
        int idx = tid + i * 256;
        int kr = idx >> 6, nc = idx & 63;
        t[kr * 66 + nc] = __float2bfloat16(src[(size_t)(k0 + kr) * N + n0 + nc]);
    }
    __syncthreads();
#pragma unroll
    for (int i = 0; i < 16; ++i) {
        int idx = tid + i * 256;
        int nr = idx >> 6, kc = idx & 63;
        dst[(size_t)(n0 + nr) * K + k0 + kc] = t[kc * 66 + nr];
    }
}

// ---------------- V transpose: qkv cols [2048..3072) -> vt[(b,h,d)][l] ----------------
__global__ __launch_bounds__(256) void vtrans(const __hip_bfloat16* __restrict__ qkv,
                                              __hip_bfloat16* __restrict__ vt) {
    const int bh = blockIdx.x, lt = blockIdx.y;
    const int b = bh >> 4, h = bh & 15;
    __shared__ __hip_bfloat16 t[64 * 66];
    const int tid = threadIdx.x;
#pragma unroll
    for (int i = 0; i < 16; ++i) {
        int idx = tid + i * 256;
        int lr = idx >> 6, d = idx & 63;
        t[lr * 66 + d] = qkv[(size_t)(b * LL + lt * 64 + lr) * 3072 + 2048 + h * 64 + d];
    }
    __syncthreads();
#pragma unroll
    for (int i = 0; i < 16; ++i) {
        int idx = tid + i * 256;
        int dr = idx >> 6, lc = idx & 63;
        vt[((size_t)bh * 64 + dr) * LL + lt * 64 + lc] = t[lc * 66 + dr];
    }
}

// ================= 256x256 8-phase GEMM (T2+T3+T4+T5) =================
// MODE 0: bf16 out + 3-range bias (QKV). MODE 2: bf16 out + bias + relu.
// MODE 4: f32 partial out (split-K): block z computes K-range [z*K/ksplit, ...),
//         writes to Cout + z*zstride (floats), no bias.
template <int MODE>
__global__ __launch_bounds__(512, 2) void gemm256(
    const __hip_bfloat16* __restrict__ A, const __hip_bfloat16* __restrict__ Bm,
    int M, int N, int K, int ksplit, size_t zstride, void* __restrict__ Cout,
    const float* __restrict__ bias0, const float* __restrict__ bias1,
    const float* __restrict__ bias2) {
    __shared__ __hip_bfloat16 lds[2][2][2][128 * 64]; // [buf][op A=0/B=1][half][r*64+e]
    const int m0 = blockIdx.x * 256, n0 = blockIdx.y * 256;
    const int tid = threadIdx.x;
    const int wid = tid >> 6, l = tid & 63;
    const int wm = wid >> 2, wn = wid & 3;
    const int lr = l & 15, lg = l >> 4;
    const int T = K / (64 * ksplit);
    const int kb = blockIdx.z * T; // K-step base for this split

    const int c0 = tid, c1 = tid + 512;
    const int r0 = c0 >> 3, s0 = (((c0 & 7) ^ (r0 & 7)) << 3);
    const int r1 = c1 >> 3, s1 = (((c1 & 7) ^ (r1 & 7)) << 3);
    const int ldst0 = wid * 512;
    const int ldst1 = 4096 + wid * 512;

#define STAGE(bi, isb, half, kt)                                                   \
    do {                                                                           \
        const __hip_bfloat16* _s = (isb) ? Bm : A;                                 \
        const int _br = ((isb) ? n0 : m0) + (half) * 128;                          \
        __hip_bfloat16* _d = &lds[bi][isb][half][0];                               \
        async_ld16(_s + (size_t)(_br + r0) * K + (size_t)(kb + (kt)) * 64 + s0, _d + ldst0); \
        async_ld16(_s + (size_t)(_br + r1) * K + (size_t)(kb + (kt)) * 64 + s1, _d + ldst1); \
    } while (0)

    f32x4 acc[8][4];
#pragma unroll
    for (int m = 0; m < 8; ++m)
#pragma unroll
        for (int n = 0; n < 4; ++n) acc[m][n] = (f32x4){0.f, 0.f, 0.f, 0.f};

    short8 aR[4][2], bR[4][2];

#define LDA(dst, bi, m, kh)                                                        \
    do {                                                                           \
        const int _ra = (m) * 16 + lr;                                             \
        const int _sl = ((kh) * 4 + lg) ^ (_ra & 7);                               \
        dst = *reinterpret_cast<const short8*>(&lds[bi][0][wm][_ra * 64 + _sl * 8]); \
    } while (0)
#define LDB(dst, bi, n, kh)                                                        \
    do {                                                                           \
        const int _rb = (wn & 1) * 64 + (n) * 16 + lr;                             \
        const int _sl = ((kh) * 4 + lg) ^ (_rb & 7);                               \
        dst = *reinterpret_cast<const short8*>(&lds[bi][1][wn >> 1][_rb * 64 + _sl * 8]); \
    } while (0)

    STAGE(0, 1, 0, 0);
    STAGE(0, 0, 0, 0);
    STAGE(0, 1, 1, 0);
    STAGE(0, 0, 1, 0);
    if (T > 1) {
        STAGE(1, 1, 0, 1);
        STAGE(1, 0, 0, 1);
        asm volatile("s_waitcnt vmcnt(4)" ::: "memory");
    } else {
        asm volatile("s_waitcnt vmcnt(0)" ::: "memory");
    }
    wg_barrier();

    for (int t = 0; t < T; ++t) {
        const int cur = t & 1, nxt = cur ^ 1;
#pragma unroll
        for (int m = 0; m < 4; ++m) {
            LDA(aR[m][0], cur, m, 0);
            LDA(aR[m][1], cur, m, 1);
        }
#pragma unroll
        for (int n = 0; n < 2; ++n) {
            LDB(bR[n][0], cur, n, 0);
            LDB(bR[n][1], cur, n, 1);
        }
        if (t + 1 < T) STAGE(nxt, 1, 1, t + 1);
        wg_barrier();
        __builtin_amdgcn_s_setprio(1);
#pragma unroll
        for (int m = 0; m < 4; ++m)
#pragma unroll
            for (int n = 0; n < 2; ++n) {
                acc[m][n] = mfma16(aR[m][0], bR[n][0], acc[m][n]);
                acc[m][n] = mfma16(aR[m][1], bR[n][1], acc[m][n]);
            }
        __builtin_amdgcn_s_setprio(0);
        wg_barrier();
#pragma unroll
        for (int n = 2; n < 4; ++n) {
            LDB(bR[n][0], cur, n, 0);
            LDB(bR[n][1], cur, n, 1);
        }
        if (t + 1 < T) STAGE(nxt, 0, 1, t + 1);
        wg_barrier();
        __builtin_amdgcn_s_setprio(1);
#pragma unroll
        for (int m = 0; m < 4; ++m)
#pragma unroll
            for (int n = 2; n < 4; ++n) {
                acc[m][n] = mfma16(aR[m][0], bR[n][0], acc[m][n]);
                acc[m][n] = mfma16(aR[m][1], bR[n][1], acc[m][n]);
            }
        __builtin_amdgcn_s_setprio(0);
        wg_barrier();
#pragma unroll
        for (int m = 0; m < 4; ++m) {
            LDA(aR[m][0], cur, m + 4, 0);
            LDA(aR[m][1], cur, m + 4, 1);
        }
        if (t + 2 < T) STAGE(cur, 1, 0, t + 2);
        wg_barrier();
        __builtin_amdgcn_s_setprio(1);
#pragma unroll
        for (int m = 0; m < 4; ++m)
#pragma unroll
            for (int n = 0; n < 2; ++n) {
                acc[m + 4][n] = mfma16(aR[m][0], bR[n][0], acc[m + 4][n]);
                acc[m + 4][n] = mfma16(aR[m][1], bR[n][1], acc[m + 4][n]);
            }
        __builtin_amdgcn_s_setprio(0);
        wg_barrier();
        if (t + 2 < T) STAGE(cur, 0, 0, t + 2);
        wg_barrier();
        __builtin_amdgcn_s_setprio(1);
#pragma unroll
        for (int m = 0; m < 4; ++m)
#pragma unroll
            for (int n = 2; n < 4; ++n) {
                acc[m + 4][n] = mfma16(aR[m][0], bR[n][0], acc[m + 4][n]);
                acc[m + 4][n] = mfma16(aR[m][1], bR[n][1], acc[m + 4][n]);
            }
        __builtin_amdgcn_s_setprio(0);
        if (t + 2 < T)
            asm volatile("s_waitcnt vmcnt(4)" ::: "memory");
        else
            asm volatile("s_waitcnt vmcnt(0)" ::: "memory");
        wg_barrier();
    }
#undef STAGE
#undef LDA
#undef LDB

    if constexpr (MODE == 4) {
        float* Cp = (float*)Cout + (size_t)blockIdx.z * zstride;
#pragma unroll
        for (int n = 0; n < 4; ++n) {
            const int col = n0 + wn * 64 + n * 16 + lr;
#pragma unroll
            for (int m = 0; m < 8; ++m) {
                const int row = m0 + wm * 128 + m * 16 + lg * 4;
#pragma unroll
                for (int r = 0; r < 4; ++r)
                    Cp[(size_t)(row + r) * N + col] = acc[m][n][r];
            }
        }
    } else {
#pragma unroll
        for (int n = 0; n < 4; ++n) {
            const int col = n0 + wn * 64 + n * 16 + lr;
            float bv;
            if constexpr (MODE == 0) {
                int s = col >> 10;
                const float* bp = (s == 0) ? bias0 : ((s == 1) ? bias1 : bias2);
                bv = bp[col & 1023];
            } else {
                bv = bias0[col];
            }
#pragma unroll
            for (int m = 0; m < 8; ++m) {
                const int row = m0 + wm * 128 + m * 16 + lg * 4;
#pragma unroll
                for (int r = 0; r < 4; ++r) {
                    float v = acc[m][n][r] + bv;
                    if constexpr (MODE == 2) v = fmaxf(v, 0.f);
                    ((__hip_bfloat16*)Cout)[(size_t)(row + r) * N + col] = __float2bfloat16(v);
                }
            }
        }
    }
}

// ---------------- flash attention v3: swapped QK^T, in-register softmax ----------------
__global__ __launch_bounds__(512) void attn3(const __hip_bfloat16* __restrict__ qkv,
                                             const __hip_bfloat16* __restrict__ vt,
                                             __hip_bfloat16* __restrict__ cat) {
    const int qt = blockIdx.x, bh = blockIdx.y;
    const int b = bh >> 4, h = bh & 15;
    const int tid = threadIdx.x, w = tid >> 6, l = tid & 63;
    const int lr = l & 15, lg = l >> 4;
    const int sw = lr & 7; // row-XOR swizzle term for K/V fragment reads

    __shared__ __hip_bfloat16 Ks[2][64 * 64];   // [kv][d], chunk-swizzled
    __shared__ __hip_bfloat16 Vs[2][64 * 64];   // [d][kv], chunk-swizzled
    __shared__ __hip_bfloat16 plds[8][16 * 72]; // per-wave P transpose, pad 72

    const size_t qrow = (size_t)(b * LL + qt * 128 + w * 16 + lr);
    const short8 qa0 = *reinterpret_cast<const short8*>(qkv + qrow * 3072 + h * 64 + lg * 8);
    const short8 qa1 = *reinterpret_cast<const short8*>(qkv + qrow * 3072 + h * 64 + 32 + lg * 8);

    const int rA = tid >> 3, sA = (((tid & 7) ^ (rA & 7)) << 3);
    const __hip_bfloat16* kg = qkv + (size_t)(b * LL + rA) * 3072 + 1024 + h * 64 + sA;
    const __hip_bfloat16* vg = vt + ((size_t)bh * 64 + rA) * LL + sA;

#define STAGE_KV(bi, k0)                                      \
    do {                                                      \
        async_ld16(kg + (size_t)(k0) * 3072, &Ks[bi][w * 512]); \
        async_ld16(vg + (k0), &Vs[bi][w * 512]);              \
    } while (0)

    float mrun = -INFINITY, lrun = 0.f;
    f32x4 oacc[4];
#pragma unroll
    for (int n = 0; n < 4; ++n) oacc[n] = (f32x4){0.f, 0.f, 0.f, 0.f};

    STAGE_KV(0, 0);
    asm volatile("s_waitcnt vmcnt(0)" ::: "memory");
    __syncthreads();

    const float SCALE = 0.18033688011112042f; // 1/sqrt(64) * log2(e)

    int cur = 0;
    for (int kt = 0; kt < 16; ++kt) {
        if (kt < 15) STAGE_KV(cur ^ 1, (kt + 1) * 64);

        f32x4 s[4];
#pragma unroll
        for (int m = 0; m < 4; ++m) {
            const int krow = m * 16 + lr;
            const short8 kf0 =
                *reinterpret_cast<const short8*>(&Ks[cur][krow * 64 + ((lg ^ sw) << 3)]);
            const short8 kf1 =
                *reinterpret_cast<const short8*>(&Ks[cur][krow * 64 + (((lg + 4) ^ sw) << 3)]);
            f32x4 t = (f32x4){0.f, 0.f, 0.f, 0.f};
            t = mfma16(kf0, qa0, t);
            t = mfma16(kf1, qa1, t);
            s[m] = t * SCALE;
        }
        float smax = s[0][0];
#pragma unroll
        for (int m = 0; m < 4; ++m)
#pragma unroll
            for (int r = 0; r < 4; ++r) smax = fmaxf(smax, s[m][r]);
        smax = fmaxf(smax, __shfl_xor(smax, 16, 64));
        smax = fmaxf(smax, __shfl_xor(smax, 32, 64));
        if (__any(smax > mrun + 8.0f)) {
            const float mnew = fmaxf(mrun, smax);
            const float alpha = exp2_fast(mrun - mnew);
            mrun = mnew;
            lrun *= alpha;
#pragma unroll
            for (int r = 0; r < 4; ++r) {
                const float aD = __shfl(alpha, lg * 4 + r, 64);
#pragma unroll
                for (int n = 0; n < 4; ++n) oacc[n][r] *= aD;
            }
        }
        float p[4][4];
        float tsum = 0.f;
#pragma unroll
        for (int m = 0; m < 4; ++m)
#pragma unroll
            for (int r = 0; r < 4; ++r) {
                p[m][r] = exp2_fast(s[m][r] - mrun);
                tsum += p[m][r];
            }
        tsum += __shfl_xor(tsum, 16, 64);
        tsum += __shfl_xor(tsum, 32, 64);
        lrun += tsum;

#pragma unroll
        for (int m = 0; m < 4; ++m) {
            uint2 d;
            d.x = cvt_pk_bf16(p[m][0], p[m][1]);
            d.y = cvt_pk_bf16(p[m][2], p[m][3]);
            *reinterpret_cast<uint2*>(&plds[w][lr * 72 + m * 16 + lg * 4]) = d;
        }
        asm volatile("s_waitcnt lgkmcnt(0)" ::: "memory");
        __builtin_amdgcn_sched_barrier(0);

        const short8 pa0 = *reinterpret_cast<const short8*>(&plds[w][lr * 72 + lg * 8]);
        const short8 pa1 = *reinterpret_cast<const short8*>(&plds[w][lr * 72 + 32 + lg * 8]);
#pragma unroll
        for (int n = 0; n < 4; ++n) {
            const int vrow = n * 16 + lr;
            const short8 vf0 =
                *reinterpret_cast<const short8*>(&Vs[cur][vrow * 64 + ((lg ^ sw) << 3)]);
            const short8 vf1 =
                *reinterpret_cast<const short8*>(&Vs[cur][vrow * 64 + (((lg + 4) ^ sw) << 3)]);
            oacc[n] = mfma16(pa0, vf0, oacc[n]);
            oacc[n] = mfma16(pa1, vf1, oacc[n]);
        }

        asm volatile("s_waitcnt vmcnt(0)" ::: "memory");
        __syncthreads();
        cur ^= 1;
    }
#undef STAGE_KV

    float rinv[4];
#pragma unroll
    for (int r = 0; r < 4; ++r) rinv[r] = 1.0f / __shfl(lrun, lg * 4 + r, 64);
#pragma unroll
    for (int n = 0; n < 4; ++n)
#pragma unroll
        for (int r = 0; r < 4; ++r) {
            const float v = oacc[n][r] * rinv[r];
            cat[(size_t)(b * LL + qt * 128 + w * 16 + lg * 4 + r) * EE + h * 64 + n * 16 + lr] =
                __float2bfloat16(v);
        }
}

// ---------------- fused split-K reduce + residual + bias + LayerNorm over E=1024 ----------------
// sum = a[i] + b[i] + c[i] + colbias[col]; out = gamma*(sum-mean)/sqrt(var+eps)+beta
__global__ __launch_bounds__(256) void ln_fused(const float* __restrict__ a,
                                                const float* __restrict__ b,
                                                const float* __restrict__ c,
                                                const float* __restrict__ colbias,
                                                const float* __restrict__ gamma,
                                                const float* __restrict__ beta,
                                                float* __restrict__ outf,
                                                __hip_bfloat16* __restrict__ outb) {
    const int row = blockIdx.x, tid = threadIdx.x;
    const size_t base = (size_t)row * EE;
    float4 x = reinterpret_cast<const float4*>(a + base)[tid];
    float4 y = reinterpret_cast<const float4*>(b + base)[tid];
    float4 z = reinterpret_cast<const float4*>(c + base)[tid];
    float4 cb = reinterpret_cast<const float4*>(colbias)[tid];
    x.x += y.x + z.x + cb.x;
    x.y += y.y + z.y + cb.y;
    x.z += y.z + z.z + cb.z;
    x.w += y.w + z.w + cb.w;
    float s = x.x + x.y + x.z + x.w;
    float s2 = x.x * x.x + x.y * x.y + x.z * x.z + x.w * x.w;
#pragma unroll
    for (int msk = 1; msk < 64; msk <<= 1) {
        s += __shfl_xor(s, msk, 64);
        s2 += __shfl_xor(s2, msk, 64);
    }
    __shared__ float red[8];
    const int w = tid >> 6, l = tid & 63;
    if (l == 0) { red[w] = s; red[4 + w] = s2; }
    __syncthreads();
    s = red[0] + red[1] + red[2] + red[3];
    s2 = red[4] + red[5] + red[6] + red[7];
    const float mean = s * (1.f / 1024.f);
    const float var = s2 * (1.f / 1024.f) - mean * mean;
    const float rstd = rsqrtf(var + 1e-10f);
    float4 g = reinterpret_cast<const float4*>(gamma)[tid];
    float4 bt = reinterpret_cast<const float4*>(beta)[tid];
    float4 o;
    o.x = g.x * (x.x - mean) * rstd + bt.x;
    o.y = g.y * (x.y - mean) * rstd + bt.y;
    o.z = g.z * (x.z - mean) * rstd + bt.z;
    o.w = g.w * (x.w - mean) * rstd + bt.w;
    reinterpret_cast<float4*>(outf + base)[tid] = o;
    if (outb) {
        ushort4 ob;
        ob.x = bf16bits(o.x); ob.y = bf16bits(o.y); ob.z = bf16bits(o.z); ob.w = bf16bits(o.w);
        reinterpret_cast<ushort4*>(outb + base)[tid] = ob;
    }
}

extern "C" void kernel_launch(void* const* d_in, const int* in_sizes, int n_in,
                              void* d_out, int out_size, void* d_ws, size_t ws_size,
                              hipStream_t stream) {
    const float* x = (const float*)d_in[0];
    const float* Wq = (const float*)d_in[1];
    const float* bq = (const float*)d_in[2];
    const float* Wk = (const float*)d_in[3];
    const float* bk = (const float*)d_in[4];
    const float* Wv = (const float*)d_in[5];
    const float* bv = (const float*)d_in[6];
    const float* Wo = (const float*)d_in[7];
    const float* bo = (const float*)d_in[8];
    const float* W1 = (const float*)d_in[9];
    const float* b1 = (const float*)d_in[10];
    const float* W2 = (const float*)d_in[11];
    const float* b2 = (const float*)d_in[12];
    const float* gamma1 = (const float*)d_in[13];
    const float* beta1 = (const float*)d_in[14];
    const float* gamma2 = (const float*)d_in[15];
    const float* beta2 = (const float*)d_in[16];
    float* out = (float*)d_out;

    char* Wb = (char*)d_ws;
    const size_t MB = (size_t)1 << 20;
    if (ws_size < 168 * MB) return;
    // Layout (live-range reuse):
    //  0-16  xb            (cvt -> QKV)           | q0 (FFN2 partial, after FFN1)
    // 16-22  wqkvt         (-> QKV)               |   (q0 spans 0-32)
    // 22-24  wot           (-> outproj)           |
    // 24-32  w1t           (-> FFN1)              |
    // 32-40  w2t           (-> FFN2)
    // 40-88  qkvb          (QKV -> attn)          | p0 40-72, p1 72-104 (outproj partials)
    // 88-104 vtb           (vtrans -> attn)       |   then hbuf 40-104 (FFN1 -> FFN2)
    // 104-120 catb         (attn -> outproj)      | out2f 104-136 (LN1 -> LN2)
    // 136-152 out2b        (LN1 -> FFN1)          | q1 136-168 (FFN2 partial -> LN2)
    __hip_bfloat16* xb = (__hip_bfloat16*)(Wb + 0 * MB);
    __hip_bfloat16* wqkvt = (__hip_bfloat16*)(Wb + 16 * MB);
    __hip_bfloat16* wot = (__hip_bfloat16*)(Wb + 22 * MB);
    __hip_bfloat16* w1t = (__hip_bfloat16*)(Wb + 24 * MB);
    __hip_bfloat16* w2t = (__hip_bfloat16*)(Wb + 32 * MB);
    __hip_bfloat16* qkvb = (__hip_bfloat16*)(Wb + 40 * MB);
    __hip_bfloat16* vtb = (__hip_bfloat16*)(Wb + 88 * MB);
    __hip_bfloat16* catb = (__hip_bfloat16*)(Wb + 104 * MB);
    float* p0 = (float*)(Wb + 40 * MB);          // outproj partials (2 x 32 MB, contiguous)
    float* out2f = (float*)(Wb + 104 * MB);      // LN1 f32 out
    __hip_bfloat16* out2b = (__hip_bfloat16*)(Wb + 136 * MB); // LN1 bf16 out
    __hip_bfloat16* hbuf = (__hip_bfloat16*)(Wb + 40 * MB);   // FFN1 out (64 MB)
    float* q0 = (float*)(Wb + 0 * MB);           // FFN2 partial z=0
    float* q1 = (float*)(Wb + 136 * MB);         // FFN2 partial z=1
    const size_t QSTRIDE = (136 * MB) / 4;       // float stride from q0 to q1

    cvt_bf16<<<8192, 256, 0, stream>>>(x, xb);
    wtrans<<<dim3(16, 1, 16), 256, 0, stream>>>(Wq, wqkvt, 1024, 64, 65536, 65536);
    wtrans<<<dim3(16, 1, 16), 256, 0, stream>>>(Wk, wqkvt + 1024 * 1024, 1024, 64, 65536, 65536);
    wtrans<<<dim3(16, 1, 16), 256, 0, stream>>>(Wv, wqkvt + 2048 * 1024, 1024, 64, 65536, 65536);
    wtrans<<<dim3(16, 16, 1), 256, 0, stream>>>(Wo, wot, 1024, 1024, 0, 0);
    wtrans<<<dim3(16, 64, 1), 256, 0, stream>>>(W1, w1t, 1024, 4096, 0, 0);
    wtrans<<<dim3(64, 16, 1), 256, 0, stream>>>(W2, w2t, 4096, 1024, 0, 0);
    // QKV projection: 8-phase 256^2
    gemm256<0><<<dim3(32, 12, 1), 512, 0, stream>>>(xb, wqkvt, 8192, 3072, 1024, 1, 0, qkvb,
                                                    bq, bk, bv);
    vtrans<<<dim3(128, 16), 256, 0, stream>>>(qkvb, vtb);
    attn3<<<dim3(8, 128), 512, 0, stream>>>(qkvb, vtb, catb);
    // output projection: split-K=2 f32 partials p0/p1 (contiguous, zstride = M*N)
    gemm256<4><<<dim3(32, 4, 2), 512, 0, stream>>>(catb, wot, 8192, 1024, 1024, 2,
                                                   (size_t)8192 * 1024, p0, nullptr, nullptr,
                                                   nullptr);
    // LN1 = LN(p0 + p1 + x + bo)
    ln_fused<<<8192, 256, 0, stream>>>(p0, p0 + (size_t)8192 * 1024, x, bo, gamma1, beta1,
                                       out2f, out2b);
    // FFN1 + ReLU: 8-phase 256^2
    gemm256<2><<<dim3(32, 16, 1), 512, 0, stream>>>(out2b, w1t, 8192, 4096, 1024, 1, 0, hbuf,
                                                    b1, nullptr, nullptr);
    // FFN2: split-K=2 f32 partials q0/q1 (zstride picks 136 MB apart)
    gemm256<4><<<dim3(32, 4, 2), 512, 0, stream>>>(hbuf, w2t, 8192, 1024, 4096, 2, QSTRIDE, q0,
                                                   nullptr, nullptr, nullptr);
    // LN2 = LN(q0 + q1 + out2 + b2) -> d_out (f32)
    ln_fused<<<8192, 256, 0, stream>>>(q0, q1, out2f, b2, gamma2, beta2, out, nullptr);
}

// Round 6
// 343.429 us; speedup vs baseline: 1.7158x; 1.1341x over previous
//
#include <hip/hip_runtime.h>
#include <hip/hip_bf16.h>

// Shapes (fixed per reference)
#define BB 8
#define LL 1024
#define EE 1024
#define HH 16
#define DHH 64
#define FFF 4096

typedef __attribute__((ext_vector_type(8))) short short8;
typedef __attribute__((ext_vector_type(4))) float f32x4;

__device__ inline f32x4 mfma16(short8 a, short8 b, f32x4 c) {
    return __builtin_amdgcn_mfma_f32_16x16x32_bf16(a, b, c, 0, 0, 0);
}

__device__ inline void async_ld16(const __hip_bfloat16* g, __hip_bfloat16* l) {
    __builtin_amdgcn_global_load_lds(
        (const __attribute__((address_space(1))) void*)g,
        (__attribute__((address_space(3))) void*)l, 16, 0, 0);
}

__device__ inline unsigned short bf16bits(float f) {
    __hip_bfloat16 h = __float2bfloat16(f);
    return *reinterpret_cast<unsigned short*>(&h);
}

__device__ inline float bf2f(unsigned short u) {
    unsigned v = ((unsigned)u) << 16;
    return *reinterpret_cast<float*>(&v);
}

__device__ inline float exp2_fast(float x) {
    float r;
    asm("v_exp_f32 %0, %1" : "=v"(r) : "v"(x));
    return r;
}

__device__ inline unsigned cvt_pk_bf16(float lo, float hi) {
    unsigned r;
    asm("v_cvt_pk_bf16_f32 %0, %1, %2" : "=v"(r) : "v"(lo), "v"(hi));
    return r;
}

// raw workgroup barrier (no implicit vmcnt(0) drain), with compiler memory fence
__device__ inline void wg_barrier() {
    asm volatile("" ::: "memory");
    __builtin_amdgcn_s_barrier();
    asm volatile("" ::: "memory");
}

// ---------------- elementwise f32 -> bf16 ----------------
__global__ __launch_bounds__(256) void cvt_bf16(const float* __restrict__ in,
                                                __hip_bfloat16* __restrict__ out) {
    size_t i = (size_t)blockIdx.x * 256 + threadIdx.x; // one float4 per thread
    float4 v = reinterpret_cast<const float4*>(in)[i];
    ushort4 o;
    o.x = bf16bits(v.x); o.y = bf16bits(v.y); o.z = bf16bits(v.z); o.w = bf16bits(v.w);
    reinterpret_cast<ushort4*>(out)[i] = o;
}

// ---------------- weight transpose+convert: dst[n*K+k] = src[k*N+n] ----------------
__global__ __launch_bounds__(256) void wtrans(const float* __restrict__ src,
                                              __hip_bfloat16* __restrict__ dst,
                                              int K, int N, long src_z, long dst_z) {
    src += (size_t)blockIdx.z * src_z;
    dst += (size_t)blockIdx.z * dst_z;
    __shared__ __hip_bfloat16 t[64 * 66]; // pad 66: strided phase conflict-free
    const int k0 = blockIdx.x * 64, n0 = blockIdx.y * 64;
    const int tid = threadIdx.x;
#pragma unroll
    for (int i = 0; i < 16; ++i) {
        int idx = tid + i * 256;
        int kr = idx >> 6, nc = idx & 63;
        t[kr * 66 + nc] = __float2bfloat16(src[(size_t)(k0 + kr) * N + n0 + nc]);
    }
    __syncthreads();
#pragma unroll
    for (int i = 0; i < 16; ++i) {
        int idx = tid + i * 256;
        int nr = idx >> 6, kc = idx & 63;
        dst[(size_t)(n0 + nr) * K + k0 + kc] = t[kc * 66 + nr];
    }
}

// ---------------- V transpose: qkv cols [2048..3072) -> vt[(b,h,d)][l] ----------------
__global__ __launch_bounds__(256) void vtrans(const __hip_bfloat16* __restrict__ qkv,
                                              __hip_bfloat16* __restrict__ vt) {
    const int bh = blockIdx.x, lt = blockIdx.y;
    const int b = bh >> 4, h = bh & 15;
    __shared__ __hip_bfloat16 t[64 * 66];
    const int tid = threadIdx.x;
#pragma unroll
    for (int i = 0; i < 16; ++i) {
        int idx = tid + i * 256;
        int lr = idx >> 6, d = idx & 63;
        t[lr * 66 + d] = qkv[(size_t)(b * LL + lt * 64 + lr) * 3072 + 2048 + h * 64 + d];
    }
    __syncthreads();
#pragma unroll
    for (int i = 0; i < 16; ++i) {
        int idx = tid + i * 256;
        int dr = idx >> 6, lc = idx & 63;
        vt[((size_t)bh * 64 + dr) * LL + lt * 64 + lc] = t[lc * 66 + dr];
    }
}

// ================= 256x256 8-phase GEMM (T1+T2+T3+T4+T5) =================
// MODE 0: bf16 out + 3-range bias (QKV). MODE 2: bf16 out + bias + relu.
// MODE 4: bf16 PARTIAL out (split-K): block z computes K-range [z*K/ksplit,...),
//         writes to (bf16*)Cout + z*zstride, no bias (bias folded into fused LN).
// Epilogue: per-wave LDS transpose [16][68] f32 (stride 68 -> <=2-way banks) then
// full-128B-line dwordx4 stores (8 lanes x 16B per row).
template <int MODE>
__global__ __launch_bounds__(512, 2) void gemm256(
    const __hip_bfloat16* __restrict__ A, const __hip_bfloat16* __restrict__ Bm,
    int M, int N, int K, int ksplit, size_t zstride, void* __restrict__ Cout,
    const float* __restrict__ bias0, const float* __restrict__ bias1,
    const float* __restrict__ bias2) {
    __shared__ __hip_bfloat16 lds[2][2][2][128 * 64]; // [buf][op A=0/B=1][half][r*64+e]
    // T1: bijective XCD swizzle over flattened (x,y); all grids here have nwg%8==0
    const int nwg = gridDim.x * gridDim.y;
    const int orig = blockIdx.y * gridDim.x + blockIdx.x;
    const int q8 = nwg >> 3, r8 = nwg & 7;
    const int xcd = orig & 7, loc = orig >> 3;
    const int swz = (xcd < r8) ? (xcd * (q8 + 1) + loc)
                               : (r8 * (q8 + 1) + (xcd - r8) * q8 + loc);
    const int m0 = (swz % gridDim.x) * 256, n0 = (swz / gridDim.x) * 256;
    const int tid = threadIdx.x;
    const int wid = tid >> 6, l = tid & 63;
    const int wm = wid >> 2, wn = wid & 3;
    const int lr = l & 15, lg = l >> 4;
    const int T = K / (64 * ksplit);
    const int kb = blockIdx.z * T; // K-step base for this split

    const int c0 = tid, c1 = tid + 512;
    const int r0 = c0 >> 3, s0 = (((c0 & 7) ^ (r0 & 7)) << 3);
    const int r1 = c1 >> 3, s1 = (((c1 & 7) ^ (r1 & 7)) << 3);
    const int ldst0 = wid * 512;
    const int ldst1 = 4096 + wid * 512;

#define STAGE(bi, isb, half, kt)                                                   \
    do {                                                                           \
        const __hip_bfloat16* _s = (isb) ? Bm : A;                                 \
        const int _br = ((isb) ? n0 : m0) + (half) * 128;                          \
        __hip_bfloat16* _d = &lds[bi][isb][half][0];                               \
        async_ld16(_s + (size_t)(_br + r0) * K + (size_t)(kb + (kt)) * 64 + s0, _d + ldst0); \
        async_ld16(_s + (size_t)(_br + r1) * K + (size_t)(kb + (kt)) * 64 + s1, _d + ldst1); \
    } while (0)

    f32x4 acc[8][4];
#pragma unroll
    for (int m = 0; m < 8; ++m)
#pragma unroll
        for (int n = 0; n < 4; ++n) acc[m][n] = (f32x4){0.f, 0.f, 0.f, 0.f};

    short8 aR[4][2], bR[4][2];

#define LDA(dst, bi, m, kh)                                                        \
    do {                                                                           \
        const int _ra = (m) * 16 + lr;                                             \
        const int _sl = ((kh) * 4 + lg) ^ (_ra & 7);                               \
        dst = *reinterpret_cast<const short8*>(&lds[bi][0][wm][_ra * 64 + _sl * 8]); \
    } while (0)
#define LDB(dst, bi, n, kh)                                                        \
    do {                                                                           \
        const int _rb = (wn & 1) * 64 + (n) * 16 + lr;                             \
        const int _sl = ((kh) * 4 + lg) ^ (_rb & 7);                               \
        dst = *reinterpret_cast<const short8*>(&lds[bi][1][wn >> 1][_rb * 64 + _sl * 8]); \
    } while (0)

    STAGE(0, 1, 0, 0);
    STAGE(0, 0, 0, 0);
    STAGE(0, 1, 1, 0);
    STAGE(0, 0, 1, 0);
    if (T > 1) {
        STAGE(1, 1, 0, 1);
        STAGE(1, 0, 0, 1);
        asm volatile("s_waitcnt vmcnt(4)" ::: "memory");
    } else {
        asm volatile("s_waitcnt vmcnt(0)" ::: "memory");
    }
    wg_barrier();

    for (int t = 0; t < T; ++t) {
        const int cur = t & 1, nxt = cur ^ 1;
#pragma unroll
        for (int m = 0; m < 4; ++m) {
            LDA(aR[m][0], cur, m, 0);
            LDA(aR[m][1], cur, m, 1);
        }
#pragma unroll
        for (int n = 0; n < 2; ++n) {
            LDB(bR[n][0], cur, n, 0);
            LDB(bR[n][1], cur, n, 1);
        }
        if (t + 1 < T) STAGE(nxt, 1, 1, t + 1);
        wg_barrier();
        __builtin_amdgcn_s_setprio(1);
#pragma unroll
        for (int m = 0; m < 4; ++m)
#pragma unroll
            for (int n = 0; n < 2; ++n) {
                acc[m][n] = mfma16(aR[m][0], bR[n][0], acc[m][n]);
                acc[m][n] = mfma16(aR[m][1], bR[n][1], acc[m][n]);
            }
        __builtin_amdgcn_s_setprio(0);
        wg_barrier();
#pragma unroll
        for (int n = 2; n < 4; ++n) {
            LDB(bR[n][0], cur, n, 0);
            LDB(bR[n][1], cur, n, 1);
        }
        if (t + 1 < T) STAGE(nxt, 0, 1, t + 1);
        wg_barrier();
        __builtin_amdgcn_s_setprio(1);
#pragma unroll
        for (int m = 0; m < 4; ++m)
#pragma unroll
            for (int n = 2; n < 4; ++n) {
                acc[m][n] = mfma16(aR[m][0], bR[n][0], acc[m][n]);
                acc[m][n] = mfma16(aR[m][1], bR[n][1], acc[m][n]);
            }
        __builtin_amdgcn_s_setprio(0);
        wg_barrier();
#pragma unroll
        for (int m = 0; m < 4; ++m) {
            LDA(aR[m][0], cur, m + 4, 0);
            LDA(aR[m][1], cur, m + 4, 1);
        }
        if (t + 2 < T) STAGE(cur, 1, 0, t + 2);
        wg_barrier();
        __builtin_amdgcn_s_setprio(1);
#pragma unroll
        for (int m = 0; m < 4; ++m)
#pragma unroll
            for (int n = 0; n < 2; ++n) {
                acc[m + 4][n] = mfma16(aR[m][0], bR[n][0], acc[m + 4][n]);
                acc[m + 4][n] = mfma16(aR[m][1], bR[n][1], acc[m + 4][n]);
            }
        __builtin_amdgcn_s_setprio(0);
        wg_barrier();
        if (t + 2 < T) STAGE(cur, 0, 0, t + 2);
        wg_barrier();
        __builtin_amdgcn_s_setprio(1);
#pragma unroll
        for (int m = 0; m < 4; ++m)
#pragma unroll
            for (int n = 2; n < 4; ++n) {
                acc[m + 4][n] = mfma16(aR[m][0], bR[n][0], acc[m + 4][n]);
                acc[m + 4][n] = mfma16(aR[m][1], bR[n][1], acc[m + 4][n]);
            }
        __builtin_amdgcn_s_setprio(0);
        if (t + 2 < T)
            asm volatile("s_waitcnt vmcnt(4)" ::: "memory");
        else
            asm volatile("s_waitcnt vmcnt(0)" ::: "memory");
        wg_barrier();
    }
#undef STAGE
#undef LDA
#undef LDB

    // ---- epilogue: per-wave LDS transpose -> full-line bf16 stores ----
    __syncthreads(); // main-loop LDS dead (final barrier already drained counters)
    float* eb = reinterpret_cast<float*>(&lds[0][0][0][0]) + wid * (16 * 68);
    const int erow = l >> 3, ec = l & 7;
    const int rowg = m0 + wm * 128;
    const int colg = n0 + wn * 64;
    float bv[4];
#pragma unroll
    for (int n = 0; n < 4; ++n) {
        if constexpr (MODE == 0) {
            const int col = colg + n * 16 + lr;
            int s = col >> 10;
            const float* bp = (s == 0) ? bias0 : ((s == 1) ? bias1 : bias2);
            bv[n] = bp[col & 1023];
        } else if constexpr (MODE == 2) {
            bv[n] = bias0[colg + n * 16 + lr];
        } else {
            bv[n] = 0.f;
        }
    }
    __hip_bfloat16* Cb = (MODE == 4)
        ? ((__hip_bfloat16*)Cout + (size_t)blockIdx.z * zstride)
        : (__hip_bfloat16*)Cout;
#pragma unroll
    for (int m = 0; m < 8; ++m) {
#pragma unroll
        for (int n = 0; n < 4; ++n)
#pragma unroll
            for (int r = 0; r < 4; ++r) {
                float v = acc[m][n][r] + bv[n];
                if constexpr (MODE == 2) v = fmaxf(v, 0.f);
                eb[(lg * 4 + r) * 68 + n * 16 + lr] = v;
            }
#pragma unroll
        for (int i = 0; i < 2; ++i) {
            const int rr = erow + i * 8;
            float4 v0 = *reinterpret_cast<float4*>(&eb[rr * 68 + ec * 8]);
            float4 v1 = *reinterpret_cast<float4*>(&eb[rr * 68 + ec * 8 + 4]);
            uint4 o;
            o.x = cvt_pk_bf16(v0.x, v0.y);
            o.y = cvt_pk_bf16(v0.z, v0.w);
            o.z = cvt_pk_bf16(v1.x, v1.y);
            o.w = cvt_pk_bf16(v1.z, v1.w);
            *reinterpret_cast<uint4*>(&Cb[(size_t)(rowg + m * 16 + rr) * N + colg + ec * 8]) = o;
        }
    }
}

// ---------------- flash attention v3: swapped QK^T, in-register softmax ----------------
__global__ __launch_bounds__(512) void attn3(const __hip_bfloat16* __restrict__ qkv,
                                             const __hip_bfloat16* __restrict__ vt,
                                             __hip_bfloat16* __restrict__ cat) {
    // T1: XCD swizzle so each XCD owns 16 consecutive bh (its 4MB KV set fits one L2)
    const int orig = blockIdx.y * 8 + blockIdx.x; // gridDim = (8, 128), nwg = 1024
    const int swz = (orig & 7) * 128 + (orig >> 3);
    const int qt = swz & 7, bh = swz >> 3;
    const int b = bh >> 4, h = bh & 15;
    const int tid = threadIdx.x, w = tid >> 6, l = tid & 63;
    const int lr = l & 15, lg = l >> 4;
    const int sw = lr & 7; // row-XOR swizzle term for K/V fragment reads

    __shared__ __hip_bfloat16 Ks[2][64 * 64];   // [kv][d], chunk-swizzled
    __shared__ __hip_bfloat16 Vs[2][64 * 64];   // [d][kv], chunk-swizzled
    __shared__ __hip_bfloat16 plds[8][16 * 72]; // per-wave P transpose, pad 72

    const size_t qrow = (size_t)(b * LL + qt * 128 + w * 16 + lr);
    const short8 qa0 = *reinterpret_cast<const short8*>(qkv + qrow * 3072 + h * 64 + lg * 8);
    const short8 qa1 = *reinterpret_cast<const short8*>(qkv + qrow * 3072 + h * 64 + 32 + lg * 8);

    const int rA = tid >> 3, sA = (((tid & 7) ^ (rA & 7)) << 3);
    const __hip_bfloat16* kg = qkv + (size_t)(b * LL + rA) * 3072 + 1024 + h * 64 + sA;
    const __hip_bfloat16* vg = vt + ((size_t)bh * 64 + rA) * LL + sA;

#define STAGE_KV(bi, k0)                                      \
    do {                                                      \
        async_ld16(kg + (size_t)(k0) * 3072, &Ks[bi][w * 512]); \
        async_ld16(vg + (k0), &Vs[bi][w * 512]);              \
    } while (0)

    float mrun = -INFINITY, lrun = 0.f;
    f32x4 oacc[4];
#pragma unroll
    for (int n = 0; n < 4; ++n) oacc[n] = (f32x4){0.f, 0.f, 0.f, 0.f};

    STAGE_KV(0, 0);
    asm volatile("s_waitcnt vmcnt(0)" ::: "memory");
    __syncthreads();

    const float SCALE = 0.18033688011112042f; // 1/sqrt(64) * log2(e)

    int cur = 0;
    for (int kt = 0; kt < 16; ++kt) {
        if (kt < 15) STAGE_KV(cur ^ 1, (kt + 1) * 64);

        f32x4 s[4];
#pragma unroll
        for (int m = 0; m < 4; ++m) {
            const int krow = m * 16 + lr;
            const short8 kf0 =
                *reinterpret_cast<const short8*>(&Ks[cur][krow * 64 + ((lg ^ sw) << 3)]);
            const short8 kf1 =
                *reinterpret_cast<const short8*>(&Ks[cur][krow * 64 + (((lg + 4) ^ sw) << 3)]);
            f32x4 t = (f32x4){0.f, 0.f, 0.f, 0.f};
            t = mfma16(kf0, qa0, t);
            t = mfma16(kf1, qa1, t);
            s[m] = t * SCALE;
        }
        float smax = s[0][0];
#pragma unroll
        for (int m = 0; m < 4; ++m)
#pragma unroll
            for (int r = 0; r < 4; ++r) smax = fmaxf(smax, s[m][r]);
        smax = fmaxf(smax, __shfl_xor(smax, 16, 64));
        smax = fmaxf(smax, __shfl_xor(smax, 32, 64));
        if (__any(smax > mrun + 8.0f)) {
            const float mnew = fmaxf(mrun, smax);
            const float alpha = exp2_fast(mrun - mnew);
            mrun = mnew;
            lrun *= alpha;
#pragma unroll
            for (int r = 0; r < 4; ++r) {
                const float aD = __shfl(alpha, lg * 4 + r, 64);
#pragma unroll
                for (int n = 0; n < 4; ++n) oacc[n][r] *= aD;
            }
        }
        float p[4][4];
        float tsum = 0.f;
#pragma unroll
        for (int m = 0; m < 4; ++m)
#pragma unroll
            for (int r = 0; r < 4; ++r) {
                p[m][r] = exp2_fast(s[m][r] - mrun);
                tsum += p[m][r];
            }
        tsum += __shfl_xor(tsum, 16, 64);
        tsum += __shfl_xor(tsum, 32, 64);
        lrun += tsum;

#pragma unroll
        for (int m = 0; m < 4; ++m) {
            uint2 d;
            d.x = cvt_pk_bf16(p[m][0], p[m][1]);
            d.y = cvt_pk_bf16(p[m][2], p[m][3]);
            *reinterpret_cast<uint2*>(&plds[w][lr * 72 + m * 16 + lg * 4]) = d;
        }
        asm volatile("s_waitcnt lgkmcnt(0)" ::: "memory");
        __builtin_amdgcn_sched_barrier(0);

        const short8 pa0 = *reinterpret_cast<const short8*>(&plds[w][lr * 72 + lg * 8]);
        const short8 pa1 = *reinterpret_cast<const short8*>(&plds[w][lr * 72 + 32 + lg * 8]);
#pragma unroll
        for (int n = 0; n < 4; ++n) {
            const int vrow = n * 16 + lr;
            const short8 vf0 =
                *reinterpret_cast<const short8*>(&Vs[cur][vrow * 64 + ((lg ^ sw) << 3)]);
            const short8 vf1 =
                *reinterpret_cast<const short8*>(&Vs[cur][vrow * 64 + (((lg + 4) ^ sw) << 3)]);
            oacc[n] = mfma16(pa0, vf0, oacc[n]);
            oacc[n] = mfma16(pa1, vf1, oacc[n]);
        }

        asm volatile("s_waitcnt vmcnt(0)" ::: "memory");
        __syncthreads();
        cur ^= 1;
    }
#undef STAGE_KV

    float rinv[4];
#pragma unroll
    for (int r = 0; r < 4; ++r) rinv[r] = 1.0f / __shfl(lrun, lg * 4 + r, 64);
#pragma unroll
    for (int n = 0; n < 4; ++n)
#pragma unroll
        for (int r = 0; r < 4; ++r) {
            const float v = oacc[n][r] * rinv[r];
            cat[(size_t)(b * LL + qt * 128 + w * 16 + lg * 4 + r) * EE + h * 64 + n * 16 + lr] =
                __float2bfloat16(v);
        }
}

// ------- fused split-K reduce (bf16 partials) + residual + bias + LayerNorm (E=1024) -------
// sum = a[i] + b[i] + c[i] + colbias[col]; out = gamma*(sum-mean)/sqrt(var+eps)+beta
__global__ __launch_bounds__(256) void ln_fused(const __hip_bfloat16* __restrict__ a,
                                                const __hip_bfloat16* __restrict__ b,
                                                const float* __restrict__ c,
                                                const float* __restrict__ colbias,
                                                const float* __restrict__ gamma,
                                                const float* __restrict__ beta,
                                                float* __restrict__ outf,
                                                __hip_bfloat16* __restrict__ outb) {
    const int row = blockIdx.x, tid = threadIdx.x;
    const size_t base = (size_t)row * EE;
    const ushort4 ua = reinterpret_cast<const ushort4*>(a + base)[tid];
    const ushort4 ub = reinterpret_cast<const ushort4*>(b + base)[tid];
    float4 z = reinterpret_cast<const float4*>(c + base)[tid];
    float4 cb = reinterpret_cast<const float4*>(colbias)[tid];
    float4 x;
    x.x = bf2f(ua.x) + bf2f(ub.x) + z.x + cb.x;
    x.y = bf2f(ua.y) + bf2f(ub.y) + z.y + cb.y;
    x.z = bf2f(ua.z) + bf2f(ub.z) + z.z + cb.z;
    x.w = bf2f(ua.w) + bf2f(ub.w) + z.w + cb.w;
    float s = x.x + x.y + x.z + x.w;
    float s2 = x.x * x.x + x.y * x.y + x.z * x.z + x.w * x.w;
#pragma unroll
    for (int msk = 1; msk < 64; msk <<= 1) {
        s += __shfl_xor(s, msk, 64);
        s2 += __shfl_xor(s2, msk, 64);
    }
    __shared__ float red[8];
    const int w = tid >> 6, l = tid & 63;
    if (l == 0) { red[w] = s; red[4 + w] = s2; }
    __syncthreads();
    s = red[0] + red[1] + red[2] + red[3];
    s2 = red[4] + red[5] + red[6] + red[7];
    const float mean = s * (1.f / 1024.f);
    const float var = s2 * (1.f / 1024.f) - mean * mean;
    const float rstd = rsqrtf(var + 1e-10f);
    float4 g = reinterpret_cast<const float4*>(gamma)[tid];
    float4 bt = reinterpret_cast<const float4*>(beta)[tid];
    float4 o;
    o.x = g.x * (x.x - mean) * rstd + bt.x;
    o.y = g.y * (x.y - mean) * rstd + bt.y;
    o.z = g.z * (x.z - mean) * rstd + bt.z;
    o.w = g.w * (x.w - mean) * rstd + bt.w;
    reinterpret_cast<float4*>(outf + base)[tid] = o;
    if (outb) {
        ushort4 ob;
        ob.x = bf16bits(o.x); ob.y = bf16bits(o.y); ob.z = bf16bits(o.z); ob.w = bf16bits(o.w);
        reinterpret_cast<ushort4*>(outb + base)[tid] = ob;
    }
}

extern "C" void kernel_launch(void* const* d_in, const int* in_sizes, int n_in,
                              void* d_out, int out_size, void* d_ws, size_t ws_size,
                              hipStream_t stream) {
    const float* x = (const float*)d_in[0];
    const float* Wq = (const float*)d_in[1];
    const float* bq = (const float*)d_in[2];
    const float* Wk = (const float*)d_in[3];
    const float* bk = (const float*)d_in[4];
    const float* Wv = (const float*)d_in[5];
    const float* bv = (const float*)d_in[6];
    const float* Wo = (const float*)d_in[7];
    const float* bo = (const float*)d_in[8];
    const float* W1 = (const float*)d_in[9];
    const float* b1 = (const float*)d_in[10];
    const float* W2 = (const float*)d_in[11];
    const float* b2 = (const float*)d_in[12];
    const float* gamma1 = (const float*)d_in[13];
    const float* beta1 = (const float*)d_in[14];
    const float* gamma2 = (const float*)d_in[15];
    const float* beta2 = (const float*)d_in[16];
    float* out = (float*)d_out;

    char* Wb = (char*)d_ws;
    const size_t MB = (size_t)1 << 20;
    if (ws_size < 168 * MB) return;
    // Layout (live-range reuse):
    //  0-16  xb (cvt->QKV)            | q0 16MB bf16 (FFN2 partial z=0 -> LN2)
    // 16-22  wqkvt (->QKV)            | q1 16MB bf16 spans 16-32 (FFN2 partial z=1)
    // 22-24  wot (->outproj)          |
    // 24-32  w1t (->FFN1)             |
    // 32-40  w2t (->FFN2)
    // 40-88  qkvb (QKV->attn)         | p0 40-56, p1 56-72 bf16 (outproj partials)
    // 88-104 vtb (vtrans->attn)       |   then hbuf 40-104 (FFN1->FFN2)
    // 104-120 catb (attn->outproj)    | out2f 104-136 (LN1->LN2)
    // 136-152 out2b (LN1->FFN1)
    __hip_bfloat16* xb = (__hip_bfloat16*)(Wb + 0 * MB);
    __hip_bfloat16* wqkvt = (__hip_bfloat16*)(Wb + 16 * MB);
    __hip_bfloat16* wot = (__hip_bfloat16*)(Wb + 22 * MB);
    __hip_bfloat16* w1t = (__hip_bfloat16*)(Wb + 24 * MB);
    __hip_bfloat16* w2t = (__hip_bfloat16*)(Wb + 32 * MB);
    __hip_bfloat16* qkvb = (__hip_bfloat16*)(Wb + 40 * MB);
    __hip_bfloat16* vtb = (__hip_bfloat16*)(Wb + 88 * MB);
    __hip_bfloat16* catb = (__hip_bfloat16*)(Wb + 104 * MB);
    __hip_bfloat16* p0 = (__hip_bfloat16*)(Wb + 40 * MB); // outproj bf16 partials (2x16MB)
    float* out2f = (float*)(Wb + 104 * MB);               // LN1 f32 out
    __hip_bfloat16* out2b = (__hip_bfloat16*)(Wb + 136 * MB);
    __hip_bfloat16* hbuf = (__hip_bfloat16*)(Wb + 40 * MB); // FFN1 out (64 MB)
    __hip_bfloat16* q0 = (__hip_bfloat16*)(Wb + 0 * MB);    // FFN2 bf16 partials (2x16MB)
    const size_t PSTRIDE = (size_t)8192 * 1024;             // bf16 elements (16 MB)

    cvt_bf16<<<8192, 256, 0, stream>>>(x, xb);
    wtrans<<<dim3(16, 1, 16), 256, 0, stream>>>(Wq, wqkvt, 1024, 64, 65536, 65536);
    wtrans<<<dim3(16, 1, 16), 256, 0, stream>>>(Wk, wqkvt + 1024 * 1024, 1024, 64, 65536, 65536);
    wtrans<<<dim3(16, 1, 16), 256, 0, stream>>>(Wv, wqkvt + 2048 * 1024, 1024, 64, 65536, 65536);
    wtrans<<<dim3(16, 16, 1), 256, 0, stream>>>(Wo, wot, 1024, 1024, 0, 0);
    wtrans<<<dim3(16, 64, 1), 256, 0, stream>>>(W1, w1t, 1024, 4096, 0, 0);
    wtrans<<<dim3(64, 16, 1), 256, 0, stream>>>(W2, w2t, 4096, 1024, 0, 0);
    // QKV projection: 8-phase 256^2
    gemm256<0><<<dim3(32, 12, 1), 512, 0, stream>>>(xb, wqkvt, 8192, 3072, 1024, 1, 0, qkvb,
                                                    bq, bk, bv);
    vtrans<<<dim3(128, 16), 256, 0, stream>>>(qkvb, vtb);
    attn3<<<dim3(8, 128), 512, 0, stream>>>(qkvb, vtb, catb);
    // output projection: split-K=2 bf16 partials p0/p1
    gemm256<4><<<dim3(32, 4, 2), 512, 0, stream>>>(catb, wot, 8192, 1024, 1024, 2, PSTRIDE, p0,
                                                   nullptr, nullptr, nullptr);
    // LN1 = LN(p0 + p1 + x + bo)
    ln_fused<<<8192, 256, 0, stream>>>(p0, p0 + PSTRIDE, x, bo, gamma1, beta1, out2f, out2b);
    // FFN1 + ReLU: 8-phase 256^2
    gemm256<2><<<dim3(32, 16, 1), 512, 0, stream>>>(out2b, w1t, 8192, 4096, 1024, 1, 0, hbuf,
                                                    b1, nullptr, nullptr);
    // FFN2: split-K=2 bf16 partials q0/q1
    gemm256<4><<<dim3(32, 4, 2), 512, 0, stream>>>(hbuf, w2t, 8192, 1024, 4096, 2, PSTRIDE, q0,
                                                   nullptr, nullptr, nullptr);
    // LN2 = LN(q0 + q1 + out2 + b2) -> d_out (f32)
    ln_fused<<<8192, 256, 0, stream>>>(q0, q0 + PSTRIDE, out2f, b2, gamma2, beta2, out, nullptr);
}

// Round 7
// 335.410 us; speedup vs baseline: 1.7569x; 1.0239x over previous
//
#include <hip/hip_runtime.h>
#include <hip/hip_bf16.h>

// Shapes (fixed per reference)
#define BB 8
#define LL 1024
#define EE 1024
#define HH 16
#define DHH 64
#define FFF 4096

typedef __attribute__((ext_vector_type(8))) short short8;
typedef __attribute__((ext_vector_type(4))) float f32x4;

__device__ inline f32x4 mfma16(short8 a, short8 b, f32x4 c) {
    return __builtin_amdgcn_mfma_f32_16x16x32_bf16(a, b, c, 0, 0, 0);
}

__device__ inline void async_ld16(const __hip_bfloat16* g, __hip_bfloat16* l) {
    __builtin_amdgcn_global_load_lds(
        (const __attribute__((address_space(1))) void*)g,
        (__attribute__((address_space(3))) void*)l, 16, 0, 0);
}

__device__ inline unsigned short bf16bits(float f) {
    __hip_bfloat16 h = __float2bfloat16(f);
    return *reinterpret_cast<unsigned short*>(&h);
}

__device__ inline float bf2f(unsigned short u) {
    unsigned v = ((unsigned)u) << 16;
    return *reinterpret_cast<float*>(&v);
}

__device__ inline float exp2_fast(float x) {
    float r;
    asm("v_exp_f32 %0, %1" : "=v"(r) : "v"(x));
    return r;
}

__device__ inline unsigned cvt_pk_bf16(float lo, float hi) {
    unsigned r;
    asm("v_cvt_pk_bf16_f32 %0, %1, %2" : "=v"(r) : "v"(lo), "v"(hi));
    return r;
}

// raw workgroup barrier (no implicit vmcnt(0) drain), with compiler memory fence
__device__ inline void wg_barrier() {
    asm volatile("" ::: "memory");
    __builtin_amdgcn_s_barrier();
    asm volatile("" ::: "memory");
}

// ---------------- elementwise f32 -> bf16 ----------------
__global__ __launch_bounds__(256) void cvt_bf16(const float* __restrict__ in,
                                                __hip_bfloat16* __restrict__ out) {
    size_t i = (size_t)blockIdx.x * 256 + threadIdx.x; // one float4 per thread
    float4 v = reinterpret_cast<const float4*>(in)[i];
    ushort4 o;
    o.x = bf16bits(v.x); o.y = bf16bits(v.y); o.z = bf16bits(v.z); o.w = bf16bits(v.w);
    reinterpret_cast<ushort4*>(out)[i] = o;
}

// ---------------- weight transpose+convert: dst[n*K+k] = src[k*N+n] ----------------
__global__ __launch_bounds__(256) void wtrans(const float* __restrict__ src,
                                              __hip_bfloat16* __restrict__ dst,
                                              int K, int N, long src_z, long dst_z) {
    src += (size_t)blockIdx.z * src_z;
    dst += (size_t)blockIdx.z * dst_z;
    __shared__ __hip_bfloat16 t[64 * 66]; // pad 66: strided phase conflict-free
    const int k0 = blockIdx.x * 64, n0 = blockIdx.y * 64;
    const int tid = threadIdx.x;
#pragma unroll
    for (int i = 0; i < 16; ++i) {
        int idx = tid + i * 256;
        int kr = idx >> 6, nc = idx & 63;
        t[kr * 66 + nc] = __float2bfloat16(src[(size_t)(k0 + kr) * N + n0 + nc]);
    }
    __syncthreads();
#pragma unroll
    for (int i = 0; i < 16; ++i) {
        int idx = tid + i * 256;
        int nr = idx >> 6, kc = idx & 63;
        dst[(size_t)(n0 + nr) * K + k0 + kc] = t[kc * 66 + nr];
    }
}

// ---------------- V transpose: qkv cols [2048..3072) -> vt[(b,h,d)][l] ----------------
__global__ __launch_bounds__(256) void vtrans(const __hip_bfloat16* __restrict__ qkv,
                                              __hip_bfloat16* __restrict__ vt) {
    const int bh = blockIdx.x, lt = blockIdx.y;
    const int b = bh >> 4, h = bh & 15;
    __shared__ __hip_bfloat16 t[64 * 66];
    const int tid = threadIdx.x;
#pragma unroll
    for (int i = 0; i < 16; ++i) {
        int idx = tid + i * 256;
        int lr = idx >> 6, d = idx & 63;
        t[lr * 66 + d] = qkv[(size_t)(b * LL + lt * 64 + lr) * 3072 + 2048 + h * 64 + d];
    }
    __syncthreads();
#pragma unroll
    for (int i = 0; i < 16; ++i) {
        int idx = tid + i * 256;
        int dr = idx >> 6, lc = idx & 63;
        vt[((size_t)bh * 64 + dr) * LL + lt * 64 + lc] = t[lc * 66 + dr];
    }
}

// ================= 256x256 8-phase GEMM (T1-clustered + T2+T3+T4+T5) =================
// MODE 0: bf16 out + 3-range bias (QKV). MODE 2: bf16 out + bias + relu.
// MODE 4: bf16 PARTIAL out (split-K): writes to (bf16*)Cout + z*zstride, no bias.
// XCD clustering: flat block id -> xcd = flat&7 (HW round-robin), rank = flat>>3.
// Each XCD owns a CM x CN cluster of 256^2 tiles: mc = xcd&3 picks the m-cluster,
// hc = xcd>>2 picks the n-cluster-half (ZX=0) or the split-K half (ZX=1).
// Working set per XCD ~6-8 MB (vs full-A sweep before) -> L2/L3 resident.
template <int MODE, int CM, int CN, int ZX>
__global__ __launch_bounds__(512, 2) void gemm256(
    const __hip_bfloat16* __restrict__ A, const __hip_bfloat16* __restrict__ Bm,
    int M, int N, int K, int ksplit, size_t zstride, void* __restrict__ Cout,
    const float* __restrict__ bias0, const float* __restrict__ bias1,
    const float* __restrict__ bias2) {
    __shared__ __hip_bfloat16 lds[2][2][2][128 * 64]; // [buf][op A=0/B=1][half][r*64+e]
    const int flat = blockIdx.x + gridDim.x * (blockIdx.y + gridDim.y * blockIdx.z);
    const int xcd = flat & 7, rank = flat >> 3;
    const int mc = xcd & 3, hc = xcd >> 2;
    const int ml = rank / CN, nl = rank % CN;
    const int mb = mc * CM + ml;
    const int nb = ZX ? nl : (hc * CN + nl);
    const int zb = ZX ? hc : 0;
    const int m0 = mb * 256, n0 = nb * 256;
    const int tid = threadIdx.x;
    const int wid = tid >> 6, l = tid & 63;
    const int wm = wid >> 2, wn = wid & 3;
    const int lr = l & 15, lg = l >> 4;
    const int T = K / (64 * ksplit);
    const int kb = zb * T; // K-step base for this split

    const int c0 = tid, c1 = tid + 512;
    const int r0 = c0 >> 3, s0 = (((c0 & 7) ^ (r0 & 7)) << 3);
    const int r1 = c1 >> 3, s1 = (((c1 & 7) ^ (r1 & 7)) << 3);
    const int ldst0 = wid * 512;
    const int ldst1 = 4096 + wid * 512;

#define STAGE(bi, isb, half, kt)                                                   \
    do {                                                                           \
        const __hip_bfloat16* _s = (isb) ? Bm : A;                                 \
        const int _br = ((isb) ? n0 : m0) + (half) * 128;                          \
        __hip_bfloat16* _d = &lds[bi][isb][half][0];                               \
        async_ld16(_s + (size_t)(_br + r0) * K + (size_t)(kb + (kt)) * 64 + s0, _d + ldst0); \
        async_ld16(_s + (size_t)(_br + r1) * K + (size_t)(kb + (kt)) * 64 + s1, _d + ldst1); \
    } while (0)

    f32x4 acc[8][4];
#pragma unroll
    for (int m = 0; m < 8; ++m)
#pragma unroll
        for (int n = 0; n < 4; ++n) acc[m][n] = (f32x4){0.f, 0.f, 0.f, 0.f};

    short8 aR[4][2], bR[4][2];

#define LDA(dst, bi, m, kh)                                                        \
    do {                                                                           \
        const int _ra = (m) * 16 + lr;                                             \
        const int _sl = ((kh) * 4 + lg) ^ (_ra & 7);                               \
        dst = *reinterpret_cast<const short8*>(&lds[bi][0][wm][_ra * 64 + _sl * 8]); \
    } while (0)
#define LDB(dst, bi, n, kh)                                                        \
    do {                                                                           \
        const int _rb = (wn & 1) * 64 + (n) * 16 + lr;                             \
        const int _sl = ((kh) * 4 + lg) ^ (_rb & 7);                               \
        dst = *reinterpret_cast<const short8*>(&lds[bi][1][wn >> 1][_rb * 64 + _sl * 8]); \
    } while (0)

    STAGE(0, 1, 0, 0);
    STAGE(0, 0, 0, 0);
    STAGE(0, 1, 1, 0);
    STAGE(0, 0, 1, 0);
    if (T > 1) {
        STAGE(1, 1, 0, 1);
        STAGE(1, 0, 0, 1);
        asm volatile("s_waitcnt vmcnt(4)" ::: "memory");
    } else {
        asm volatile("s_waitcnt vmcnt(0)" ::: "memory");
    }
    wg_barrier();

    for (int t = 0; t < T; ++t) {
        const int cur = t & 1, nxt = cur ^ 1;
#pragma unroll
        for (int m = 0; m < 4; ++m) {
            LDA(aR[m][0], cur, m, 0);
            LDA(aR[m][1], cur, m, 1);
        }
#pragma unroll
        for (int n = 0; n < 2; ++n) {
            LDB(bR[n][0], cur, n, 0);
            LDB(bR[n][1], cur, n, 1);
        }
        if (t + 1 < T) STAGE(nxt, 1, 1, t + 1);
        wg_barrier();
        __builtin_amdgcn_s_setprio(1);
#pragma unroll
        for (int m = 0; m < 4; ++m)
#pragma unroll
            for (int n = 0; n < 2; ++n) {
                acc[m][n] = mfma16(aR[m][0], bR[n][0], acc[m][n]);
                acc[m][n] = mfma16(aR[m][1], bR[n][1], acc[m][n]);
            }
        __builtin_amdgcn_s_setprio(0);
        wg_barrier();
#pragma unroll
        for (int n = 2; n < 4; ++n) {
            LDB(bR[n][0], cur, n, 0);
            LDB(bR[n][1], cur, n, 1);
        }
        if (t + 1 < T) STAGE(nxt, 0, 1, t + 1);
        wg_barrier();
        __builtin_amdgcn_s_setprio(1);
#pragma unroll
        for (int m = 0; m < 4; ++m)
#pragma unroll
            for (int n = 2; n < 4; ++n) {
                acc[m][n] = mfma16(aR[m][0], bR[n][0], acc[m][n]);
                acc[m][n] = mfma16(aR[m][1], bR[n][1], acc[m][n]);
            }
        __builtin_amdgcn_s_setprio(0);
        wg_barrier();
#pragma unroll
        for (int m = 0; m < 4; ++m) {
            LDA(aR[m][0], cur, m + 4, 0);
            LDA(aR[m][1], cur, m + 4, 1);
        }
        if (t + 2 < T) STAGE(cur, 1, 0, t + 2);
        wg_barrier();
        __builtin_amdgcn_s_setprio(1);
#pragma unroll
        for (int m = 0; m < 4; ++m)
#pragma unroll
            for (int n = 0; n < 2; ++n) {
                acc[m + 4][n] = mfma16(aR[m][0], bR[n][0], acc[m + 4][n]);
                acc[m + 4][n] = mfma16(aR[m][1], bR[n][1], acc[m + 4][n]);
            }
        __builtin_amdgcn_s_setprio(0);
        wg_barrier();
        if (t + 2 < T) STAGE(cur, 0, 0, t + 2);
        wg_barrier();
        __builtin_amdgcn_s_setprio(1);
#pragma unroll
        for (int m = 0; m < 4; ++m)
#pragma unroll
            for (int n = 2; n < 4; ++n) {
                acc[m + 4][n] = mfma16(aR[m][0], bR[n][0], acc[m + 4][n]);
                acc[m + 4][n] = mfma16(aR[m][1], bR[n][1], acc[m + 4][n]);
            }
        __builtin_amdgcn_s_setprio(0);
        if (t + 2 < T)
            asm volatile("s_waitcnt vmcnt(4)" ::: "memory");
        else
            asm volatile("s_waitcnt vmcnt(0)" ::: "memory");
        wg_barrier();
    }
#undef STAGE
#undef LDA
#undef LDB

    // ---- epilogue: per-wave LDS transpose -> full-line bf16 stores ----
    __syncthreads(); // main-loop LDS dead (final barrier already drained counters)
    float* eb = reinterpret_cast<float*>(&lds[0][0][0][0]) + wid * (16 * 68);
    const int erow = l >> 3, ec = l & 7;
    const int rowg = m0 + wm * 128;
    const int colg = n0 + wn * 64;
    float bv[4];
#pragma unroll
    for (int n = 0; n < 4; ++n) {
        if constexpr (MODE == 0) {
            const int col = colg + n * 16 + lr;
            int s = col >> 10;
            const float* bp = (s == 0) ? bias0 : ((s == 1) ? bias1 : bias2);
            bv[n] = bp[col & 1023];
        } else if constexpr (MODE == 2) {
            bv[n] = bias0[colg + n * 16 + lr];
        } else {
            bv[n] = 0.f;
        }
    }
    __hip_bfloat16* Cb = (MODE == 4)
        ? ((__hip_bfloat16*)Cout + (size_t)zb * zstride)
        : (__hip_bfloat16*)Cout;
#pragma unroll
    for (int m = 0; m < 8; ++m) {
#pragma unroll
        for (int n = 0; n < 4; ++n)
#pragma unroll
            for (int r = 0; r < 4; ++r) {
                float v = acc[m][n][r] + bv[n];
                if constexpr (MODE == 2) v = fmaxf(v, 0.f);
                eb[(lg * 4 + r) * 68 + n * 16 + lr] = v;
            }
#pragma unroll
        for (int i = 0; i < 2; ++i) {
            const int rr = erow + i * 8;
            float4 v0 = *reinterpret_cast<float4*>(&eb[rr * 68 + ec * 8]);
            float4 v1 = *reinterpret_cast<float4*>(&eb[rr * 68 + ec * 8 + 4]);
            uint4 o;
            o.x = cvt_pk_bf16(v0.x, v0.y);
            o.y = cvt_pk_bf16(v0.z, v0.w);
            o.z = cvt_pk_bf16(v1.x, v1.y);
            o.w = cvt_pk_bf16(v1.z, v1.w);
            *reinterpret_cast<uint4*>(&Cb[(size_t)(rowg + m * 16 + rr) * N + colg + ec * 8]) = o;
        }
    }
}

// ---------------- flash attention v3: swapped QK^T, in-register softmax ----------------
__global__ __launch_bounds__(512) void attn3(const __hip_bfloat16* __restrict__ qkv,
                                             const __hip_bfloat16* __restrict__ vt,
                                             __hip_bfloat16* __restrict__ cat) {
    // T1: XCD swizzle so each XCD owns 16 consecutive bh (its 4MB KV set fits one L2)
    const int orig = blockIdx.y * 8 + blockIdx.x; // gridDim = (8, 128), nwg = 1024
    const int swz = (orig & 7) * 128 + (orig >> 3);
    const int qt = swz & 7, bh = swz >> 3;
    const int b = bh >> 4, h = bh & 15;
    const int tid = threadIdx.x, w = tid >> 6, l = tid & 63;
    const int lr = l & 15, lg = l >> 4;
    const int sw = lr & 7; // row-XOR swizzle term for K/V fragment reads

    __shared__ __hip_bfloat16 Ks[2][64 * 64];   // [kv][d], chunk-swizzled
    __shared__ __hip_bfloat16 Vs[2][64 * 64];   // [d][kv], chunk-swizzled
    __shared__ __hip_bfloat16 plds[8][16 * 72]; // per-wave P transpose, pad 72

    const size_t qrow = (size_t)(b * LL + qt * 128 + w * 16 + lr);
    const short8 qa0 = *reinterpret_cast<const short8*>(qkv + qrow * 3072 + h * 64 + lg * 8);
    const short8 qa1 = *reinterpret_cast<const short8*>(qkv + qrow * 3072 + h * 64 + 32 + lg * 8);

    const int rA = tid >> 3, sA = (((tid & 7) ^ (rA & 7)) << 3);
    const __hip_bfloat16* kg = qkv + (size_t)(b * LL + rA) * 3072 + 1024 + h * 64 + sA;
    const __hip_bfloat16* vg = vt + ((size_t)bh * 64 + rA) * LL + sA;

#define STAGE_KV(bi, k0)                                      \
    do {                                                      \
        async_ld16(kg + (size_t)(k0) * 3072, &Ks[bi][w * 512]); \
        async_ld16(vg + (k0), &Vs[bi][w * 512]);              \
    } while (0)

    float mrun = -INFINITY, lrun = 0.f;
    f32x4 oacc[4];
#pragma unroll
    for (int n = 0; n < 4; ++n) oacc[n] = (f32x4){0.f, 0.f, 0.f, 0.f};

    STAGE_KV(0, 0);
    asm volatile("s_waitcnt vmcnt(0)" ::: "memory");
    __syncthreads();

    const float SCALE = 0.18033688011112042f; // 1/sqrt(64) * log2(e)

    int cur = 0;
    for (int kt = 0; kt < 16; ++kt) {
        if (kt < 15) STAGE_KV(cur ^ 1, (kt + 1) * 64);

        f32x4 s[4];
#pragma unroll
        for (int m = 0; m < 4; ++m) {
            const int krow = m * 16 + lr;
            const short8 kf0 =
                *reinterpret_cast<const short8*>(&Ks[cur][krow * 64 + ((lg ^ sw) << 3)]);
            const short8 kf1 =
                *reinterpret_cast<const short8*>(&Ks[cur][krow * 64 + (((lg + 4) ^ sw) << 3)]);
            f32x4 t = (f32x4){0.f, 0.f, 0.f, 0.f};
            t = mfma16(kf0, qa0, t);
            t = mfma16(kf1, qa1, t);
            s[m] = t * SCALE;
        }
        float smax = s[0][0];
#pragma unroll
        for (int m = 0; m < 4; ++m)
#pragma unroll
            for (int r = 0; r < 4; ++r) smax = fmaxf(smax, s[m][r]);
        smax = fmaxf(smax, __shfl_xor(smax, 16, 64));
        smax = fmaxf(smax, __shfl_xor(smax, 32, 64));
        if (__any(smax > mrun + 8.0f)) {
            const float mnew = fmaxf(mrun, smax);
            const float alpha = exp2_fast(mrun - mnew);
            mrun = mnew;
            lrun *= alpha;
#pragma unroll
            for (int r = 0; r < 4; ++r) {
                const float aD = __shfl(alpha, lg * 4 + r, 64);
#pragma unroll
                for (int n = 0; n < 4; ++n) oacc[n][r] *= aD;
            }
        }
        float p[4][4];
        float tsum = 0.f;
#pragma unroll
        for (int m = 0; m < 4; ++m)
#pragma unroll
            for (int r = 0; r < 4; ++r) {
                p[m][r] = exp2_fast(s[m][r] - mrun);
                tsum += p[m][r];
            }
        tsum += __shfl_xor(tsum, 16, 64);
        tsum += __shfl_xor(tsum, 32, 64);
        lrun += tsum;

#pragma unroll
        for (int m = 0; m < 4; ++m) {
            uint2 d;
            d.x = cvt_pk_bf16(p[m][0], p[m][1]);
            d.y = cvt_pk_bf16(p[m][2], p[m][3]);
            *reinterpret_cast<uint2*>(&plds[w][lr * 72 + m * 16 + lg * 4]) = d;
        }
        asm volatile("s_waitcnt lgkmcnt(0)" ::: "memory");
        __builtin_amdgcn_sched_barrier(0);

        const short8 pa0 = *reinterpret_cast<const short8*>(&plds[w][lr * 72 + lg * 8]);
        const short8 pa1 = *reinterpret_cast<const short8*>(&plds[w][lr * 72 + 32 + lg * 8]);
#pragma unroll
        for (int n = 0; n < 4; ++n) {
            const int vrow = n * 16 + lr;
            const short8 vf0 =
                *reinterpret_cast<const short8*>(&Vs[cur][vrow * 64 + ((lg ^ sw) << 3)]);
            const short8 vf1 =
                *reinterpret_cast<const short8*>(&Vs[cur][vrow * 64 + (((lg + 4) ^ sw) << 3)]);
            oacc[n] = mfma16(pa0, vf0, oacc[n]);
            oacc[n] = mfma16(pa1, vf1, oacc[n]);
        }

        asm volatile("s_waitcnt vmcnt(0)" ::: "memory");
        __syncthreads();
        cur ^= 1;
    }
#undef STAGE_KV

    float rinv[4];
#pragma unroll
    for (int r = 0; r < 4; ++r) rinv[r] = 1.0f / __shfl(lrun, lg * 4 + r, 64);
#pragma unroll
    for (int n = 0; n < 4; ++n)
#pragma unroll
        for (int r = 0; r < 4; ++r) {
            const float v = oacc[n][r] * rinv[r];
            cat[(size_t)(b * LL + qt * 128 + w * 16 + lg * 4 + r) * EE + h * 64 + n * 16 + lr] =
                __float2bfloat16(v);
        }
}

// ------- fused split-K reduce (bf16 partials) + residual + bias + LayerNorm (E=1024) -------
// sum = a[i] + b[i] + c[i] + colbias[col]; out = gamma*(sum-mean)/sqrt(var+eps)+beta
__global__ __launch_bounds__(256) void ln_fused(const __hip_bfloat16* __restrict__ a,
                                                const __hip_bfloat16* __restrict__ b,
                                                const float* __restrict__ c,
                                                const float* __restrict__ colbias,
                                                const float* __restrict__ gamma,
                                                const float* __restrict__ beta,
                                                float* __restrict__ outf,
                                                __hip_bfloat16* __restrict__ outb) {
    const int row = blockIdx.x, tid = threadIdx.x;
    const size_t base = (size_t)row * EE;
    const ushort4 ua = reinterpret_cast<const ushort4*>(a + base)[tid];
    const ushort4 ub = reinterpret_cast<const ushort4*>(b + base)[tid];
    float4 z = reinterpret_cast<const float4*>(c + base)[tid];
    float4 cb = reinterpret_cast<const float4*>(colbias)[tid];
    float4 x;
    x.x = bf2f(ua.x) + bf2f(ub.x) + z.x + cb.x;
    x.y = bf2f(ua.y) + bf2f(ub.y) + z.y + cb.y;
    x.z = bf2f(ua.z) + bf2f(ub.z) + z.z + cb.z;
    x.w = bf2f(ua.w) + bf2f(ub.w) + z.w + cb.w;
    float s = x.x + x.y + x.z + x.w;
    float s2 = x.x * x.x + x.y * x.y + x.z * x.z + x.w * x.w;
#pragma unroll
    for (int msk = 1; msk < 64; msk <<= 1) {
        s += __shfl_xor(s, msk, 64);
        s2 += __shfl_xor(s2, msk, 64);
    }
    __shared__ float red[8];
    const int w = tid >> 6, l = tid & 63;
    if (l == 0) { red[w] = s; red[4 + w] = s2; }
    __syncthreads();
    s = red[0] + red[1] + red[2] + red[3];
    s2 = red[4] + red[5] + red[6] + red[7];
    const float mean = s * (1.f / 1024.f);
    const float var = s2 * (1.f / 1024.f) - mean * mean;
    const float rstd = rsqrtf(var + 1e-10f);
    float4 g = reinterpret_cast<const float4*>(gamma)[tid];
    float4 bt = reinterpret_cast<const float4*>(beta)[tid];
    float4 o;
    o.x = g.x * (x.x - mean) * rstd + bt.x;
    o.y = g.y * (x.y - mean) * rstd + bt.y;
    o.z = g.z * (x.z - mean) * rstd + bt.z;
    o.w = g.w * (x.w - mean) * rstd + bt.w;
    reinterpret_cast<float4*>(outf + base)[tid] = o;
    if (outb) {
        ushort4 ob;
        ob.x = bf16bits(o.x); ob.y = bf16bits(o.y); ob.z = bf16bits(o.z); ob.w = bf16bits(o.w);
        reinterpret_cast<ushort4*>(outb + base)[tid] = ob;
    }
}

extern "C" void kernel_launch(void* const* d_in, const int* in_sizes, int n_in,
                              void* d_out, int out_size, void* d_ws, size_t ws_size,
                              hipStream_t stream) {
    const float* x = (const float*)d_in[0];
    const float* Wq = (const float*)d_in[1];
    const float* bq = (const float*)d_in[2];
    const float* Wk = (const float*)d_in[3];
    const float* bk = (const float*)d_in[4];
    const float* Wv = (const float*)d_in[5];
    const float* bv = (const float*)d_in[6];
    const float* Wo = (const float*)d_in[7];
    const float* bo = (const float*)d_in[8];
    const float* W1 = (const float*)d_in[9];
    const float* b1 = (const float*)d_in[10];
    const float* W2 = (const float*)d_in[11];
    const float* b2 = (const float*)d_in[12];
    const float* gamma1 = (const float*)d_in[13];
    const float* beta1 = (const float*)d_in[14];
    const float* gamma2 = (const float*)d_in[15];
    const float* beta2 = (const float*)d_in[16];
    float* out = (float*)d_out;

    char* Wb = (char*)d_ws;
    const size_t MB = (size_t)1 << 20;
    if (ws_size < 168 * MB) return;
    __hip_bfloat16* xb = (__hip_bfloat16*)(Wb + 0 * MB);
    __hip_bfloat16* wqkvt = (__hip_bfloat16*)(Wb + 16 * MB);
    __hip_bfloat16* wot = (__hip_bfloat16*)(Wb + 22 * MB);
    __hip_bfloat16* w1t = (__hip_bfloat16*)(Wb + 24 * MB);
    __hip_bfloat16* w2t = (__hip_bfloat16*)(Wb + 32 * MB);
    __hip_bfloat16* qkvb = (__hip_bfloat16*)(Wb + 40 * MB);
    __hip_bfloat16* vtb = (__hip_bfloat16*)(Wb + 88 * MB);
    __hip_bfloat16* catb = (__hip_bfloat16*)(Wb + 104 * MB);
    __hip_bfloat16* p0 = (__hip_bfloat16*)(Wb + 40 * MB); // outproj bf16 partials (2x16MB)
    float* out2f = (float*)(Wb + 104 * MB);               // LN1 f32 out
    __hip_bfloat16* out2b = (__hip_bfloat16*)(Wb + 136 * MB);
    __hip_bfloat16* hbuf = (__hip_bfloat16*)(Wb + 40 * MB); // FFN1 out (64 MB)
    __hip_bfloat16* q0 = (__hip_bfloat16*)(Wb + 0 * MB);    // FFN2 bf16 partials (2x16MB)
    const size_t PSTRIDE = (size_t)8192 * 1024;             // bf16 elements (16 MB)

    cvt_bf16<<<8192, 256, 0, stream>>>(x, xb);
    wtrans<<<dim3(16, 1, 16), 256, 0, stream>>>(Wq, wqkvt, 1024, 64, 65536, 65536);
    wtrans<<<dim3(16, 1, 16), 256, 0, stream>>>(Wk, wqkvt + 1024 * 1024, 1024, 64, 65536, 65536);
    wtrans<<<dim3(16, 1, 16), 256, 0, stream>>>(Wv, wqkvt + 2048 * 1024, 1024, 64, 65536, 65536);
    wtrans<<<dim3(16, 16, 1), 256, 0, stream>>>(Wo, wot, 1024, 1024, 0, 0);
    wtrans<<<dim3(16, 64, 1), 256, 0, stream>>>(W1, w1t, 1024, 4096, 0, 0);
    wtrans<<<dim3(64, 16, 1), 256, 0, stream>>>(W2, w2t, 4096, 1024, 0, 0);
    // QKV projection: grid 32x12, per-XCD cluster 8m x 6n
    gemm256<0, 8, 6, 0><<<dim3(32, 12, 1), 512, 0, stream>>>(xb, wqkvt, 8192, 3072, 1024, 1, 0,
                                                             qkvb, bq, bk, bv);
    vtrans<<<dim3(128, 16), 256, 0, stream>>>(qkvb, vtb);
    attn3<<<dim3(8, 128), 512, 0, stream>>>(qkvb, vtb, catb);
    // output projection: split-K=2; per-XCD cluster 8m x 4n, K-half from xcd
    gemm256<4, 8, 4, 1><<<dim3(32, 4, 2), 512, 0, stream>>>(catb, wot, 8192, 1024, 1024, 2,
                                                            PSTRIDE, p0, nullptr, nullptr,
                                                            nullptr);
    // LN1 = LN(p0 + p1 + x + bo)
    ln_fused<<<8192, 256, 0, stream>>>(p0, p0 + PSTRIDE, x, bo, gamma1, beta1, out2f, out2b);
    // FFN1 + ReLU: grid 32x16, per-XCD cluster 8m x 8n
    gemm256<2, 8, 8, 0><<<dim3(32, 16, 1), 512, 0, stream>>>(out2b, w1t, 8192, 4096, 1024, 1, 0,
                                                             hbuf, b1, nullptr, nullptr);
    // FFN2: split-K=2; per-XCD cluster 8m x 4n, K-half from xcd
    gemm256<4, 8, 4, 1><<<dim3(32, 4, 2), 512, 0, stream>>>(hbuf, w2t, 8192, 1024, 4096, 2,
                                                            PSTRIDE, q0, nullptr, nullptr,
                                                            nullptr);
    // LN2 = LN(q0 + q1 + out2 + b2) -> d_out (f32)
    ln_fused<<<8192, 256, 0, stream>>>(q0, q0 + PSTRIDE, out2f, b2, gamma2, beta2, out, nullptr);
}